// Round 1
// baseline (1048.995 us; speedup 1.0000x reference)
//
#include <hip/hip_runtime.h>

#define NFEAT 128
#define NCLS  10

static inline size_t alignup(size_t x) { return (x + 255) & ~size_t(255); }

// ---------------- precompute kernels ----------------

__global__ void init_kernel(int* __restrict__ deg, int* __restrict__ cnt, int n) {
  int i = blockIdx.x * blockDim.x + threadIdx.x;
  if (i < n) { deg[i] = 1; cnt[i] = 0; }   // deg=1 accounts for the self-loop
}

__global__ void count_deg(const int* __restrict__ dst, int* __restrict__ deg, int e) {
  int i = blockIdx.x * blockDim.x + threadIdx.x;
  int stride = gridDim.x * blockDim.x;
  for (; i < e; i += stride) atomicAdd(&deg[dst[i]], 1);
}

__global__ void compute_dis(const int* __restrict__ deg, float* __restrict__ dis, int n) {
  int i = blockIdx.x * blockDim.x + threadIdx.x;
  if (i < n) dis[i] = rsqrtf((float)deg[i]);
}

// single-block exclusive scan (N=100k -> ~98 chunks of 1024; takes a few us)
__global__ __launch_bounds__(1024) void scan_exclusive(const int* __restrict__ deg,
                                                       int* __restrict__ row_ptr, int n) {
  __shared__ int sbuf[1024];
  int t = threadIdx.x;
  int carry = 0;
  for (int base = 0; base < n; base += 1024) {
    int x = (base + t < n) ? deg[base + t] : 0;
    sbuf[t] = x;
    __syncthreads();
    for (int off = 1; off < 1024; off <<= 1) {
      int v = (t >= off) ? sbuf[t - off] : 0;
      __syncthreads();
      sbuf[t] += v;
      __syncthreads();
    }
    int incl = sbuf[t];
    if (base + t < n) row_ptr[base + t] = carry + incl - x;
    int tot = sbuf[1023];
    __syncthreads();
    carry += tot;
  }
  if (t == 0) row_ptr[n] = carry;
}

// counting-sort fill: items [0,E) are edges, [E, E+N) are self-loops
__global__ void fill_csr(const int* __restrict__ ei, const float* __restrict__ dis,
                         const int* __restrict__ row_ptr, int* __restrict__ cnt,
                         int2* __restrict__ ev, int nE, int total) {
  int i = blockIdx.x * blockDim.x + threadIdx.x;
  int stride = gridDim.x * blockDim.x;
  for (; i < total; i += stride) {
    int s, d;
    if (i < nE) { s = ei[i]; d = ei[nE + i]; }
    else        { s = i - nE; d = s; }
    int pos = atomicAdd(&cnt[d], 1);
    int idx = row_ptr[d] + pos;
    float v = dis[s] * dis[d];
    ev[idx] = make_int2(s, __float_as_int(v));
  }
}

// ---------------- dense GEMM: C[nrows x 128] = A[nrows x 128] @ W[128 x 128] ----------------

#define BM 128
#define BN 128
#define BK 32

__global__ __launch_bounds__(256) void gemm128(const float* __restrict__ A,
                                               const float* __restrict__ W,
                                               float* __restrict__ C, int nrows) {
  __shared__ float As[BK][BM + 4];   // transposed A tile: As[k][m]
  __shared__ float Ws[BK][BN + 4];
  const int tid = threadIdx.x;
  const int row0 = blockIdx.x * BM;
  const int tx = tid & 15;           // 16 col-groups
  const int ty = tid >> 4;           // 16 row-groups
  float acc[8][8];
  #pragma unroll
  for (int i = 0; i < 8; ++i)
    #pragma unroll
    for (int j = 0; j < 8; ++j) acc[i][j] = 0.f;

  for (int k0 = 0; k0 < NFEAT; k0 += BK) {
    // load A tile (128 x 32), transposed into LDS
    #pragma unroll
    for (int i = 0; i < 4; ++i) {
      int r = (tid >> 3) + i * 32;        // 0..127
      int c = (tid & 7) * 4;              // 0..28
      float4 a = make_float4(0.f, 0.f, 0.f, 0.f);
      if (row0 + r < nrows)
        a = *(const float4*)&A[(size_t)(row0 + r) * NFEAT + k0 + c];
      As[c + 0][r] = a.x; As[c + 1][r] = a.y; As[c + 2][r] = a.z; As[c + 3][r] = a.w;
    }
    // load W tile (32 x 128)
    #pragma unroll
    for (int i = 0; i < 4; ++i) {
      int kk = (tid >> 5) + i * 8;        // 0..31
      int c = (tid & 31) * 4;             // 0..124
      *(float4*)&Ws[kk][c] = *(const float4*)&W[(size_t)(k0 + kk) * BN + c];
    }
    __syncthreads();
    #pragma unroll 4
    for (int kk = 0; kk < BK; ++kk) {
      float a[8], w[8];
      #pragma unroll
      for (int i = 0; i < 8; ++i) a[i] = As[kk][ty * 8 + i];
      #pragma unroll
      for (int j = 0; j < 8; ++j) w[j] = Ws[kk][tx * 8 + j];
      #pragma unroll
      for (int i = 0; i < 8; ++i)
        #pragma unroll
        for (int j = 0; j < 8; ++j) acc[i][j] += a[i] * w[j];
    }
    __syncthreads();
  }
  #pragma unroll
  for (int i = 0; i < 8; ++i) {
    int r = row0 + ty * 8 + i;
    if (r < nrows) {
      *(float4*)&C[(size_t)r * BN + tx * 8 + 0] =
          make_float4(acc[i][0], acc[i][1], acc[i][2], acc[i][3]);
      *(float4*)&C[(size_t)r * BN + tx * 8 + 4] =
          make_float4(acc[i][4], acc[i][5], acc[i][6], acc[i][7]);
    }
  }
}

// ---------------- sparse aggregation: out[v] = b + sum_e val[e]*hw[col[e]] ----------------

__global__ __launch_bounds__(256) void aggregate(const float* __restrict__ hw,
                                                 const int* __restrict__ row_ptr,
                                                 const int2* __restrict__ ev,
                                                 const float* __restrict__ bias,
                                                 float* __restrict__ out,
                                                 int relu, int n) {
  const int wave = threadIdx.x >> 6;
  const int lane = threadIdx.x & 63;
  const int v = blockIdx.x * 4 + wave;
  if (v >= n) return;
  const int beg = row_ptr[v], end = row_ptr[v + 1];
  float2 acc;
  acc.x = bias[lane * 2];
  acc.y = bias[lane * 2 + 1];
  for (int e = beg; e < end; ++e) {
    int2 p = ev[e];                                  // broadcast 8B load
    float w = __int_as_float(p.y);
    float2 h2 = *(const float2*)&hw[(size_t)p.x * NFEAT + lane * 2];
    acc.x += w * h2.x;
    acc.y += w * h2.y;
  }
  if (relu) { acc.x = fmaxf(acc.x, 0.f); acc.y = fmaxf(acc.y, 0.f); }
  *(float2*)&out[(size_t)v * NFEAT + lane * 2] = acc;
}

// ---------------- fused final linear + log_softmax ----------------

__global__ __launch_bounds__(256) void final_layer(const float* __restrict__ h,
                                                   const float* __restrict__ Wl,
                                                   const float* __restrict__ bl,
                                                   float* __restrict__ out, int n) {
  __shared__ float Ws[NFEAT * NCLS];
  for (int i = threadIdx.x; i < NFEAT * NCLS; i += 256) Ws[i] = Wl[i];
  __syncthreads();
  const int wave = threadIdx.x >> 6;
  const int lane = threadIdx.x & 63;
  const int v = blockIdx.x * 4 + wave;
  if (v >= n) return;
  float2 h2 = *(const float2*)&h[(size_t)v * NFEAT + lane * 2];
  float p[NCLS];
  #pragma unroll
  for (int c = 0; c < NCLS; ++c)
    p[c] = h2.x * Ws[(lane * 2) * NCLS + c] + h2.y * Ws[(lane * 2 + 1) * NCLS + c];
  #pragma unroll
  for (int off = 32; off >= 1; off >>= 1)
    #pragma unroll
    for (int c = 0; c < NCLS; ++c)
      p[c] += __shfl_xor(p[c], off, 64);
  #pragma unroll
  for (int c = 0; c < NCLS; ++c) p[c] += bl[c];
  float m = p[0];
  #pragma unroll
  for (int c = 1; c < NCLS; ++c) m = fmaxf(m, p[c]);
  float s = 0.f;
  #pragma unroll
  for (int c = 0; c < NCLS; ++c) s += expf(p[c] - m);
  float lse = m + logf(s);
  if (lane < NCLS) {
    float sel = 0.f;
    #pragma unroll
    for (int c = 0; c < NCLS; ++c)
      if (lane == c) sel = p[c];
    out[(size_t)v * NCLS + lane] = sel - lse;
  }
}

// ---------------- launcher ----------------

extern "C" void kernel_launch(void* const* d_in, const int* in_sizes, int n_in,
                              void* d_out, int out_size, void* d_ws, size_t ws_size,
                              hipStream_t stream) {
  const float* x  = (const float*)d_in[0];
  const int*   ei = (const int*)d_in[1];
  const float* W1 = (const float*)d_in[2];
  const float* b1 = (const float*)d_in[3];
  const float* W2 = (const float*)d_in[4];
  const float* b2 = (const float*)d_in[5];
  const float* W3 = (const float*)d_in[6];
  const float* b3 = (const float*)d_in[7];
  const float* Wl = (const float*)d_in[8];
  const float* bl = (const float*)d_in[9];
  float* out = (float*)d_out;

  const int nN = in_sizes[0] / NFEAT;   // 100000
  const int nE = in_sizes[1] / 2;       // 1600000
  const int total = nN + nE;

  char* ws = (char*)d_ws;
  int*   deg     = (int*)ws;                       ws += alignup((size_t)nN * 4);
  float* dis     = (float*)ws;                     ws += alignup((size_t)nN * 4);
  int*   row_ptr = (int*)ws;                       ws += alignup((size_t)(nN + 1) * 4);
  int*   cnt     = (int*)ws;                       ws += alignup((size_t)nN * 4);
  int2*  ev      = (int2*)ws;                      ws += alignup((size_t)total * 8);
  float* bufA    = (float*)ws;                     ws += alignup((size_t)nN * NFEAT * 4);
  float* bufB    = (float*)ws;                     ws += alignup((size_t)nN * NFEAT * 4);

  const int nb256 = (nN + 255) / 256;
  init_kernel<<<nb256, 256, 0, stream>>>(deg, cnt, nN);
  count_deg<<<1024, 256, 0, stream>>>(ei + nE, deg, nE);   // dst row of edge_index
  compute_dis<<<nb256, 256, 0, stream>>>(deg, dis, nN);
  scan_exclusive<<<1, 1024, 0, stream>>>(deg, row_ptr, nN);
  fill_csr<<<2048, 256, 0, stream>>>(ei, dis, row_ptr, cnt, ev, nE, total);

  const int gemm_grid = (nN + BM - 1) / BM;
  const int node_grid = (nN + 3) / 4;

  // layer 1
  gemm128<<<gemm_grid, 256, 0, stream>>>(x, W1, bufB, nN);
  aggregate<<<node_grid, 256, 0, stream>>>(bufB, row_ptr, ev, b1, bufA, 1, nN);
  // layer 2
  gemm128<<<gemm_grid, 256, 0, stream>>>(bufA, W2, bufB, nN);
  aggregate<<<node_grid, 256, 0, stream>>>(bufB, row_ptr, ev, b2, bufA, 1, nN);
  // layer 3
  gemm128<<<gemm_grid, 256, 0, stream>>>(bufA, W3, bufB, nN);
  aggregate<<<node_grid, 256, 0, stream>>>(bufB, row_ptr, ev, b3, bufA, 0, nN);
  // final linear + log_softmax
  final_layer<<<node_grid, 256, 0, stream>>>(bufA, Wl, bl, out, nN);
}

// Round 2
// 695.916 us; speedup vs baseline: 1.5074x; 1.5074x over previous
//
#include <hip/hip_runtime.h>

#define NFEAT 128
#define NCLS  10
#define NCP   16   // padded class count (alignment)

static inline size_t alignup(size_t x) { return (x + 255) & ~size_t(255); }

// ---------------- precompute kernels ----------------

__global__ void init_kernel(int* __restrict__ deg, int* __restrict__ cnt, int n) {
  int i = blockIdx.x * blockDim.x + threadIdx.x;
  if (i < n) { deg[i] = 1; cnt[i] = 0; }   // deg=1 accounts for the self-loop
}

__global__ void count_deg(const int* __restrict__ dst, int* __restrict__ deg, int e) {
  int i = blockIdx.x * blockDim.x + threadIdx.x;
  int stride = gridDim.x * blockDim.x;
  for (; i < e; i += stride) atomicAdd(&deg[dst[i]], 1);
}

__global__ void compute_dis(const int* __restrict__ deg, float* __restrict__ dis, int n) {
  int i = blockIdx.x * blockDim.x + threadIdx.x;
  if (i < n) dis[i] = rsqrtf((float)deg[i]);
}

// hierarchical scan: per-block scan + block-sums scan + offset add
__global__ __launch_bounds__(1024) void scan_block(const int* __restrict__ deg,
                                                   int* __restrict__ row_ptr,
                                                   int* __restrict__ block_sums, int n) {
  __shared__ int sbuf[1024];
  const int t = threadIdx.x;
  const int base = blockIdx.x * 1024;
  int x = (base + t < n) ? deg[base + t] : 0;
  sbuf[t] = x;
  __syncthreads();
  for (int off = 1; off < 1024; off <<= 1) {
    int v = (t >= off) ? sbuf[t - off] : 0;
    __syncthreads();
    sbuf[t] += v;
    __syncthreads();
  }
  if (base + t < n) row_ptr[base + t] = sbuf[t] - x;   // block-local exclusive
  if (t == 1023) block_sums[blockIdx.x] = sbuf[1023];
}

__global__ __launch_bounds__(1024) void scan_sums(int* __restrict__ block_sums,
                                                  int* __restrict__ row_ptr,
                                                  int nb, int n) {
  __shared__ int sbuf[1024];
  const int t = threadIdx.x;
  int x = (t < nb) ? block_sums[t] : 0;
  sbuf[t] = x;
  __syncthreads();
  for (int off = 1; off < 1024; off <<= 1) {
    int v = (t >= off) ? sbuf[t - off] : 0;
    __syncthreads();
    sbuf[t] += v;
    __syncthreads();
  }
  if (t < nb) block_sums[t] = sbuf[t] - x;             // exclusive block offsets
  if (t == nb - 1) row_ptr[n] = sbuf[t];               // grand total
}

__global__ void scan_add(int* __restrict__ row_ptr, const int* __restrict__ block_sums, int n) {
  int i = blockIdx.x * blockDim.x + threadIdx.x;
  if (i < n) row_ptr[i] += block_sums[i >> 10];
}

// counting-sort fill: items [0,E) are edges, [E, E+N) are self-loops
__global__ void fill_csr(const int* __restrict__ ei, const float* __restrict__ dis,
                         const int* __restrict__ row_ptr, int* __restrict__ cnt,
                         int2* __restrict__ ev, int nE, int total) {
  int i = blockIdx.x * blockDim.x + threadIdx.x;
  int stride = gridDim.x * blockDim.x;
  for (; i < total; i += stride) {
    int s, d;
    if (i < nE) { s = ei[i]; d = ei[nE + i]; }
    else        { s = i - nE; d = s; }
    int pos = atomicAdd(&cnt[d], 1);
    int idx = row_ptr[d] + pos;
    float v = dis[s] * dis[d];
    ev[idx] = make_int2(s, __float_as_int(v));
  }
}

// fold W3@Wl -> Wf[128x16], b3@Wl + bl -> bf[16]
__global__ __launch_bounds__(256) void fold_weights(const float* __restrict__ W3,
                                                    const float* __restrict__ Wl,
                                                    const float* __restrict__ b3,
                                                    const float* __restrict__ bl,
                                                    float* __restrict__ Wf,
                                                    float* __restrict__ bf) {
  int t = blockIdx.x * blockDim.x + threadIdx.x;
  if (t < NFEAT * NCP) {
    int r = t >> 4, c = t & 15;
    float s = 0.f;
    if (c < NCLS) {
      for (int k = 0; k < NFEAT; ++k) s += W3[r * NFEAT + k] * Wl[k * NCLS + c];
    }
    Wf[t] = s;
  }
  if (t < NCP) {
    float s = 0.f;
    if (t < NCLS) {
      s = bl[t];
      for (int k = 0; k < NFEAT; ++k) s += b3[k] * Wl[k * NCLS + t];
    }
    bf[t] = s;
  }
}

// ---------------- dense GEMM: C[nrows x 128] = A[nrows x 128] @ W[128 x 128] ----------------

#define BM 128
#define BN 128
#define BK 32

__global__ __launch_bounds__(256) void gemm128(const float* __restrict__ A,
                                               const float* __restrict__ W,
                                               float* __restrict__ C, int nrows) {
  __shared__ float As[BK][BM + 4];   // transposed A tile: As[k][m]  (row = 528B, 16B aligned)
  __shared__ float Ws[BK][BN + 4];
  const int tid = threadIdx.x;
  const int row0 = blockIdx.x * BM;
  const int tx = tid & 15;           // 16 col-groups
  const int ty = tid >> 4;           // 16 row-groups
  float acc[8][8];
  #pragma unroll
  for (int i = 0; i < 8; ++i)
    #pragma unroll
    for (int j = 0; j < 8; ++j) acc[i][j] = 0.f;

  for (int k0 = 0; k0 < NFEAT; k0 += BK) {
    #pragma unroll
    for (int i = 0; i < 4; ++i) {
      int r = (tid >> 3) + i * 32;        // 0..127
      int c = (tid & 7) * 4;              // 0..28
      float4 a = make_float4(0.f, 0.f, 0.f, 0.f);
      if (row0 + r < nrows)
        a = *(const float4*)&A[(size_t)(row0 + r) * NFEAT + k0 + c];
      As[c + 0][r] = a.x; As[c + 1][r] = a.y; As[c + 2][r] = a.z; As[c + 3][r] = a.w;
    }
    #pragma unroll
    for (int i = 0; i < 4; ++i) {
      int kk = (tid >> 5) + i * 8;        // 0..31
      int c = (tid & 31) * 4;             // 0..124
      *(float4*)&Ws[kk][c] = *(const float4*)&W[(size_t)(k0 + kk) * BN + c];
    }
    __syncthreads();
    #pragma unroll 4
    for (int kk = 0; kk < BK; ++kk) {
      float4 a0 = *(const float4*)&As[kk][ty * 8];
      float4 a1 = *(const float4*)&As[kk][ty * 8 + 4];
      float4 w0 = *(const float4*)&Ws[kk][tx * 8];
      float4 w1 = *(const float4*)&Ws[kk][tx * 8 + 4];
      float a[8] = {a0.x, a0.y, a0.z, a0.w, a1.x, a1.y, a1.z, a1.w};
      float w[8] = {w0.x, w0.y, w0.z, w0.w, w1.x, w1.y, w1.z, w1.w};
      #pragma unroll
      for (int i = 0; i < 8; ++i)
        #pragma unroll
        for (int j = 0; j < 8; ++j) acc[i][j] += a[i] * w[j];
    }
    __syncthreads();
  }
  #pragma unroll
  for (int i = 0; i < 8; ++i) {
    int r = row0 + ty * 8 + i;
    if (r < nrows) {
      *(float4*)&C[(size_t)r * BN + tx * 8 + 0] =
          make_float4(acc[i][0], acc[i][1], acc[i][2], acc[i][3]);
      *(float4*)&C[(size_t)r * BN + tx * 8 + 4] =
          make_float4(acc[i][4], acc[i][5], acc[i][6], acc[i][7]);
    }
  }
}

// ---------------- sparse aggregation (128 feats): half-wave float4, 4 gathers in flight ----

__global__ __launch_bounds__(256) void aggregate(const float* __restrict__ hw,
                                                 const int* __restrict__ row_ptr,
                                                 const int2* __restrict__ ev,
                                                 const float* __restrict__ bias,
                                                 float* __restrict__ out,
                                                 int relu, int n) {
  const int wave = threadIdx.x >> 6;
  const int lane = threadIdx.x & 63;
  const int v = blockIdx.x * 4 + wave;
  if (v >= n) return;
  const int beg = row_ptr[v], end = row_ptr[v + 1];
  const int half = lane >> 5;        // 0/1: which edge parity this half-wave handles
  const int hl = lane & 31;          // feature group: floats hl*4 .. hl*4+3
  float4 acc = make_float4(0.f, 0.f, 0.f, 0.f);
  int e = beg + half;
  for (; e + 2 < end; e += 4) {      // 2 edges per half per iter -> 4 gathers in flight
    int2 p0 = ev[e];
    int2 p1 = ev[e + 2];
    float w0 = __int_as_float(p0.y);
    float w1 = __int_as_float(p1.y);
    float4 h0 = *(const float4*)&hw[(size_t)p0.x * NFEAT + hl * 4];
    float4 h1 = *(const float4*)&hw[(size_t)p1.x * NFEAT + hl * 4];
    acc.x += w0 * h0.x + w1 * h1.x;
    acc.y += w0 * h0.y + w1 * h1.y;
    acc.z += w0 * h0.z + w1 * h1.z;
    acc.w += w0 * h0.w + w1 * h1.w;
  }
  for (; e < end; e += 2) {
    int2 p = ev[e];
    float w = __int_as_float(p.y);
    float4 h = *(const float4*)&hw[(size_t)p.x * NFEAT + hl * 4];
    acc.x += w * h.x; acc.y += w * h.y; acc.z += w * h.z; acc.w += w * h.w;
  }
  acc.x += __shfl_xor(acc.x, 32);
  acc.y += __shfl_xor(acc.y, 32);
  acc.z += __shfl_xor(acc.z, 32);
  acc.w += __shfl_xor(acc.w, 32);
  if (half == 0) {
    float4 b = *(const float4*)&bias[hl * 4];
    acc.x += b.x; acc.y += b.y; acc.z += b.z; acc.w += b.w;
    if (relu) {
      acc.x = fmaxf(acc.x, 0.f); acc.y = fmaxf(acc.y, 0.f);
      acc.z = fmaxf(acc.z, 0.f); acc.w = fmaxf(acc.w, 0.f);
    }
    *(float4*)&out[(size_t)v * NFEAT + hl * 4] = acc;
  }
}

// ---------------- thin GEMM: G[N x 16] = A[N x 128] @ Wf[128 x 16] ----------------

__global__ __launch_bounds__(256) void gemm_small(const float* __restrict__ A,
                                                  const float* __restrict__ Wf,
                                                  float* __restrict__ G, int n) {
  __shared__ float Ws[NFEAT * NCP];  // 8 KB
  for (int i = threadIdx.x; i < NFEAT * NCP; i += 256) Ws[i] = Wf[i];
  __syncthreads();
  const int wave = threadIdx.x >> 6;
  const int lane = threadIdx.x & 63;
  const int v = blockIdx.x * 4 + wave;
  if (v >= n) return;
  float2 h2 = *(const float2*)&A[(size_t)v * NFEAT + lane * 2];
  float p[NCP];
  #pragma unroll
  for (int c = 0; c < NCP; ++c)
    p[c] = h2.x * Ws[(lane * 2) * NCP + c] + h2.y * Ws[(lane * 2 + 1) * NCP + c];
  #pragma unroll
  for (int off = 32; off >= 1; off >>= 1)
    #pragma unroll
    for (int c = 0; c < NCP; ++c)
      p[c] += __shfl_xor(p[c], off);
  if (lane < NCP) G[(size_t)v * NCP + lane] = p[lane];
}

// ---------------- fused sparse aggregation (16 feats) + bias + log_softmax ----------------

__global__ __launch_bounds__(256) void agg_logits(const float* __restrict__ G,
                                                  const int* __restrict__ row_ptr,
                                                  const int2* __restrict__ ev,
                                                  const float* __restrict__ bf,
                                                  float* __restrict__ out, int n) {
  const int wave = threadIdx.x >> 6;
  const int lane = threadIdx.x & 63;
  const int v = blockIdx.x * 4 + wave;
  if (v >= n) return;
  const int beg = row_ptr[v], end = row_ptr[v + 1];
  const int g = lane >> 4;           // 4 edge groups
  const int f = lane & 15;           // feature (class) index
  float acc = 0.f;
  int e = beg + g;
  for (; e + 4 < end; e += 8) {      // 2 edges per group per iter -> 8 gathers in flight
    int2 p0 = ev[e];
    int2 p1 = ev[e + 4];
    acc += __int_as_float(p0.y) * G[(size_t)p0.x * NCP + f]
         + __int_as_float(p1.y) * G[(size_t)p1.x * NCP + f];
  }
  for (; e < end; e += 4) {
    int2 p = ev[e];
    acc += __int_as_float(p.y) * G[(size_t)p.x * NCP + f];
  }
  acc += __shfl_xor(acc, 16);
  acc += __shfl_xor(acc, 32);
  float logit = acc + bf[f];
  float pv = (f < NCLS) ? logit : -INFINITY;
  float m = pv;
  #pragma unroll
  for (int s = 8; s >= 1; s >>= 1) m = fmaxf(m, __shfl_xor(m, s));
  float ex = (f < NCLS) ? expf(logit - m) : 0.f;
  float ssum = ex;
  #pragma unroll
  for (int s = 8; s >= 1; s >>= 1) ssum += __shfl_xor(ssum, s);
  float lse = m + logf(ssum);
  if (g == 0 && f < NCLS) out[(size_t)v * NCLS + f] = logit - lse;
}

// ---------------- launcher ----------------

extern "C" void kernel_launch(void* const* d_in, const int* in_sizes, int n_in,
                              void* d_out, int out_size, void* d_ws, size_t ws_size,
                              hipStream_t stream) {
  const float* x  = (const float*)d_in[0];
  const int*   ei = (const int*)d_in[1];
  const float* W1 = (const float*)d_in[2];
  const float* b1 = (const float*)d_in[3];
  const float* W2 = (const float*)d_in[4];
  const float* b2 = (const float*)d_in[5];
  const float* W3 = (const float*)d_in[6];
  const float* b3 = (const float*)d_in[7];
  const float* Wl = (const float*)d_in[8];
  const float* bl = (const float*)d_in[9];
  float* out = (float*)d_out;

  const int nN = in_sizes[0] / NFEAT;   // 100000
  const int nE = in_sizes[1] / 2;       // 1600000
  const int total = nN + nE;
  const int nb1024 = (nN + 1023) / 1024;

  char* ws = (char*)d_ws;
  int*   deg     = (int*)ws;     ws += alignup((size_t)nN * 4);
  float* dis     = (float*)ws;   ws += alignup((size_t)nN * 4);
  int*   row_ptr = (int*)ws;     ws += alignup((size_t)(nN + 1) * 4);
  int*   cnt     = (int*)ws;     ws += alignup((size_t)nN * 4);
  int*   bsums   = (int*)ws;     ws += alignup((size_t)nb1024 * 4);
  float* Wf      = (float*)ws;   ws += alignup((size_t)NFEAT * NCP * 4);
  float* bf      = (float*)ws;   ws += alignup((size_t)NCP * 4);
  int2*  ev      = (int2*)ws;    ws += alignup((size_t)total * 8);
  float* bufA    = (float*)ws;   ws += alignup((size_t)nN * NFEAT * 4);
  float* bufB    = (float*)ws;   ws += alignup((size_t)nN * NFEAT * 4);
  float* G       = bufB;         // alias: bufB is free during layer 3

  const int nb256 = (nN + 255) / 256;
  init_kernel<<<nb256, 256, 0, stream>>>(deg, cnt, nN);
  count_deg<<<1024, 256, 0, stream>>>(ei + nE, deg, nE);
  compute_dis<<<nb256, 256, 0, stream>>>(deg, dis, nN);
  scan_block<<<nb1024, 1024, 0, stream>>>(deg, row_ptr, bsums, nN);
  scan_sums<<<1, 1024, 0, stream>>>(bsums, row_ptr, nb1024, nN);
  scan_add<<<nb256, 256, 0, stream>>>(row_ptr, bsums, nN);
  fill_csr<<<2048, 256, 0, stream>>>(ei, dis, row_ptr, cnt, ev, nE, total);
  fold_weights<<<8, 256, 0, stream>>>(W3, Wl, b3, bl, Wf, bf);

  const int gemm_grid = (nN + BM - 1) / BM;
  const int node_grid = (nN + 3) / 4;

  // layer 1
  gemm128<<<gemm_grid, 256, 0, stream>>>(x, W1, bufB, nN);
  aggregate<<<node_grid, 256, 0, stream>>>(bufB, row_ptr, ev, b1, bufA, 1, nN);
  // layer 2
  gemm128<<<gemm_grid, 256, 0, stream>>>(bufA, W2, bufB, nN);
  aggregate<<<node_grid, 256, 0, stream>>>(bufB, row_ptr, ev, b2, bufA, 1, nN);
  // layer 3 folded with classifier: logits = Agg(H2 @ (W3@Wl)) + (b3@Wl + bl)
  gemm_small<<<node_grid, 256, 0, stream>>>(bufA, Wf, G, nN);
  agg_logits<<<node_grid, 256, 0, stream>>>(G, row_ptr, ev, bf, out, nN);
}

// Round 3
// 566.655 us; speedup vs baseline: 1.8512x; 1.2281x over previous
//
#include <hip/hip_runtime.h>

#define NFEAT 128
#define NCLS  10
#define NCP   16   // padded class count (alignment)

static inline size_t alignup(size_t x) { return (x + 255) & ~size_t(255); }

// ---------------- precompute kernels ----------------

__global__ void init_kernel(int* __restrict__ deg, int* __restrict__ cnt, int n) {
  int i = blockIdx.x * blockDim.x + threadIdx.x;
  if (i < n) { deg[i] = 1; cnt[i] = 0; }   // deg=1 accounts for the self-loop
}

__global__ void count_deg(const int* __restrict__ dst, int* __restrict__ deg, int e) {
  int i = blockIdx.x * blockDim.x + threadIdx.x;
  int stride = gridDim.x * blockDim.x;
  for (; i < e; i += stride) atomicAdd(&deg[dst[i]], 1);
}

__global__ void compute_dis(const int* __restrict__ deg, float* __restrict__ dis, int n) {
  int i = blockIdx.x * blockDim.x + threadIdx.x;
  if (i < n) dis[i] = rsqrtf((float)deg[i]);
}

// hierarchical scan: per-block scan + block-sums scan + offset add
__global__ __launch_bounds__(1024) void scan_block(const int* __restrict__ deg,
                                                   int* __restrict__ row_ptr,
                                                   int* __restrict__ block_sums, int n) {
  __shared__ int sbuf[1024];
  const int t = threadIdx.x;
  const int base = blockIdx.x * 1024;
  int x = (base + t < n) ? deg[base + t] : 0;
  sbuf[t] = x;
  __syncthreads();
  for (int off = 1; off < 1024; off <<= 1) {
    int v = (t >= off) ? sbuf[t - off] : 0;
    __syncthreads();
    sbuf[t] += v;
    __syncthreads();
  }
  if (base + t < n) row_ptr[base + t] = sbuf[t] - x;   // block-local exclusive
  if (t == 1023) block_sums[blockIdx.x] = sbuf[1023];
}

__global__ __launch_bounds__(1024) void scan_sums(int* __restrict__ block_sums,
                                                  int* __restrict__ row_ptr,
                                                  int nb, int n) {
  __shared__ int sbuf[1024];
  const int t = threadIdx.x;
  int x = (t < nb) ? block_sums[t] : 0;
  sbuf[t] = x;
  __syncthreads();
  for (int off = 1; off < 1024; off <<= 1) {
    int v = (t >= off) ? sbuf[t - off] : 0;
    __syncthreads();
    sbuf[t] += v;
    __syncthreads();
  }
  if (t < nb) block_sums[t] = sbuf[t] - x;             // exclusive block offsets
  if (t == nb - 1) row_ptr[n] = sbuf[t];               // grand total
}

__global__ void scan_add(int* __restrict__ row_ptr, const int* __restrict__ block_sums, int n) {
  int i = blockIdx.x * blockDim.x + threadIdx.x;
  if (i < n) row_ptr[i] += block_sums[i >> 10];
}

// counting-sort fill: items [0,E) are edges, [E, E+N) are self-loops
__global__ void fill_csr(const int* __restrict__ ei, const float* __restrict__ dis,
                         const int* __restrict__ row_ptr, int* __restrict__ cnt,
                         int2* __restrict__ ev, int nE, int total) {
  int i = blockIdx.x * blockDim.x + threadIdx.x;
  int stride = gridDim.x * blockDim.x;
  for (; i < total; i += stride) {
    int s, d;
    if (i < nE) { s = ei[i]; d = ei[nE + i]; }
    else        { s = i - nE; d = s; }
    int pos = atomicAdd(&cnt[d], 1);
    int idx = row_ptr[d] + pos;
    float v = dis[s] * dis[d];
    ev[idx] = make_int2(s, __float_as_int(v));
  }
}

// fold W3@Wl -> Wf[128x16], b3@Wl + bl -> bf[16]
__global__ __launch_bounds__(256) void fold_weights(const float* __restrict__ W3,
                                                    const float* __restrict__ Wl,
                                                    const float* __restrict__ b3,
                                                    const float* __restrict__ bl,
                                                    float* __restrict__ Wf,
                                                    float* __restrict__ bf) {
  int t = blockIdx.x * blockDim.x + threadIdx.x;
  if (t < NFEAT * NCP) {
    int r = t >> 4, c = t & 15;
    float s = 0.f;
    if (c < NCLS) {
      for (int k = 0; k < NFEAT; ++k) s += W3[r * NFEAT + k] * Wl[k * NCLS + c];
    }
    Wf[t] = s;
  }
  if (t < NCP) {
    float s = 0.f;
    if (t < NCLS) {
      s = bl[t];
      for (int k = 0; k < NFEAT; ++k) s += b3[k] * Wl[k * NCLS + t];
    }
    bf[t] = s;
  }
}

// ---------------- dense GEMM: C[nrows x 128] = A[nrows x 128] @ W[128 x 128] ----------------

#define BM 128
#define BN 128
#define BK 32

__global__ __launch_bounds__(256) void gemm128(const float* __restrict__ A,
                                               const float* __restrict__ W,
                                               float* __restrict__ C, int nrows) {
  __shared__ float As[BK][BM + 4];   // transposed A tile: As[k][m]
  __shared__ float Ws[BK][BN + 4];
  const int tid = threadIdx.x;
  const int row0 = blockIdx.x * BM;
  const int tx = tid & 15;           // 16 col-groups
  const int ty = tid >> 4;           // 16 row-groups
  float acc[8][8];
  #pragma unroll
  for (int i = 0; i < 8; ++i)
    #pragma unroll
    for (int j = 0; j < 8; ++j) acc[i][j] = 0.f;

  for (int k0 = 0; k0 < NFEAT; k0 += BK) {
    #pragma unroll
    for (int i = 0; i < 4; ++i) {
      int r = (tid >> 3) + i * 32;        // 0..127
      int c = (tid & 7) * 4;              // 0..28
      float4 a = make_float4(0.f, 0.f, 0.f, 0.f);
      if (row0 + r < nrows)
        a = *(const float4*)&A[(size_t)(row0 + r) * NFEAT + k0 + c];
      As[c + 0][r] = a.x; As[c + 1][r] = a.y; As[c + 2][r] = a.z; As[c + 3][r] = a.w;
    }
    #pragma unroll
    for (int i = 0; i < 4; ++i) {
      int kk = (tid >> 5) + i * 8;        // 0..31
      int c = (tid & 31) * 4;             // 0..124
      *(float4*)&Ws[kk][c] = *(const float4*)&W[(size_t)(k0 + kk) * BN + c];
    }
    __syncthreads();
    #pragma unroll 4
    for (int kk = 0; kk < BK; ++kk) {
      float4 a0 = *(const float4*)&As[kk][ty * 8];
      float4 a1 = *(const float4*)&As[kk][ty * 8 + 4];
      float4 w0 = *(const float4*)&Ws[kk][tx * 8];
      float4 w1 = *(const float4*)&Ws[kk][tx * 8 + 4];
      float a[8] = {a0.x, a0.y, a0.z, a0.w, a1.x, a1.y, a1.z, a1.w};
      float w[8] = {w0.x, w0.y, w0.z, w0.w, w1.x, w1.y, w1.z, w1.w};
      #pragma unroll
      for (int i = 0; i < 8; ++i)
        #pragma unroll
        for (int j = 0; j < 8; ++j) acc[i][j] += a[i] * w[j];
    }
    __syncthreads();
  }
  #pragma unroll
  for (int i = 0; i < 8; ++i) {
    int r = row0 + ty * 8 + i;
    if (r < nrows) {
      *(float4*)&C[(size_t)r * BN + tx * 8 + 0] =
          make_float4(acc[i][0], acc[i][1], acc[i][2], acc[i][3]);
      *(float4*)&C[(size_t)r * BN + tx * 8 + 4] =
          make_float4(acc[i][4], acc[i][5], acc[i][6], acc[i][7]);
    }
  }
}

// ---------------- sparse aggregation (128 feats): half-wave float4, 8 gathers in flight ----

__global__ __launch_bounds__(256) void aggregate(const float* __restrict__ hw,
                                                 const int* __restrict__ row_ptr,
                                                 const int2* __restrict__ ev,
                                                 const float* __restrict__ bias,
                                                 float* __restrict__ out,
                                                 int relu, int n) {
  const int wave = threadIdx.x >> 6;
  const int lane = threadIdx.x & 63;
  const int v = blockIdx.x * 4 + wave;
  if (v >= n) return;
  const int beg = row_ptr[v], end = row_ptr[v + 1];
  const int half = lane >> 5;        // 0/1: edge parity handled by this half-wave
  const int hl = lane & 31;          // feature group: floats hl*4 .. hl*4+3
  float4 acc = make_float4(0.f, 0.f, 0.f, 0.f);
  int e = beg + half;
  for (; e + 6 < end; e += 8) {      // 4 edges per half per iter -> 8 gathers in flight
    int2 p0 = ev[e];
    int2 p1 = ev[e + 2];
    int2 p2 = ev[e + 4];
    int2 p3 = ev[e + 6];
    float w0 = __int_as_float(p0.y);
    float w1 = __int_as_float(p1.y);
    float w2 = __int_as_float(p2.y);
    float w3 = __int_as_float(p3.y);
    float4 h0 = *(const float4*)&hw[(size_t)p0.x * NFEAT + hl * 4];
    float4 h1 = *(const float4*)&hw[(size_t)p1.x * NFEAT + hl * 4];
    float4 h2 = *(const float4*)&hw[(size_t)p2.x * NFEAT + hl * 4];
    float4 h3 = *(const float4*)&hw[(size_t)p3.x * NFEAT + hl * 4];
    acc.x += w0 * h0.x + w1 * h1.x + w2 * h2.x + w3 * h3.x;
    acc.y += w0 * h0.y + w1 * h1.y + w2 * h2.y + w3 * h3.y;
    acc.z += w0 * h0.z + w1 * h1.z + w2 * h2.z + w3 * h3.z;
    acc.w += w0 * h0.w + w1 * h1.w + w2 * h2.w + w3 * h3.w;
  }
  for (; e < end; e += 2) {
    int2 p = ev[e];
    float w = __int_as_float(p.y);
    float4 h = *(const float4*)&hw[(size_t)p.x * NFEAT + hl * 4];
    acc.x += w * h.x; acc.y += w * h.y; acc.z += w * h.z; acc.w += w * h.w;
  }
  acc.x += __shfl_xor(acc.x, 32);
  acc.y += __shfl_xor(acc.y, 32);
  acc.z += __shfl_xor(acc.z, 32);
  acc.w += __shfl_xor(acc.w, 32);
  if (half == 0) {
    float4 b = *(const float4*)&bias[hl * 4];
    acc.x += b.x; acc.y += b.y; acc.z += b.z; acc.w += b.w;
    if (relu) {
      acc.x = fmaxf(acc.x, 0.f); acc.y = fmaxf(acc.y, 0.f);
      acc.z = fmaxf(acc.z, 0.f); acc.w = fmaxf(acc.w, 0.f);
    }
    *(float4*)&out[(size_t)v * NFEAT + hl * 4] = acc;
  }
}

// ---------------- thin GEMM: G[N x 16] = A[N x 128] @ Wf[128 x 16] ----------------
// Thread-per-node: acc[16] in VGPRs, Wf read from LDS at wave-uniform addresses
// (pure broadcast, zero bank conflicts), no cross-lane reduction at all.

__global__ __launch_bounds__(256) void gemm_small(const float* __restrict__ A,
                                                  const float* __restrict__ Wf,
                                                  float* __restrict__ G, int n) {
  __shared__ float Ws[NFEAT * NCP];  // 8 KB
  for (int i = threadIdx.x; i < NFEAT * NCP; i += 256) Ws[i] = Wf[i];
  __syncthreads();
  const int v = blockIdx.x * 256 + threadIdx.x;
  if (v >= n) return;
  const float* Arow = A + (size_t)v * NFEAT;
  float acc[NCP];
  #pragma unroll
  for (int c = 0; c < NCP; ++c) acc[c] = 0.f;
  #pragma unroll 4
  for (int k = 0; k < NFEAT; k += 4) {
    float4 a = *(const float4*)&Arow[k];
    float av[4] = {a.x, a.y, a.z, a.w};
    #pragma unroll
    for (int j = 0; j < 4; ++j) {
      #pragma unroll
      for (int cq = 0; cq < NCP; cq += 4) {
        float4 w = *(const float4*)&Ws[(k + j) * NCP + cq];
        acc[cq + 0] += av[j] * w.x;
        acc[cq + 1] += av[j] * w.y;
        acc[cq + 2] += av[j] * w.z;
        acc[cq + 3] += av[j] * w.w;
      }
    }
  }
  #pragma unroll
  for (int cq = 0; cq < NCP; cq += 4)
    *(float4*)&G[(size_t)v * NCP + cq] =
        make_float4(acc[cq], acc[cq + 1], acc[cq + 2], acc[cq + 3]);
}

// ---------------- fused sparse aggregation (16 feats) + bias + log_softmax ----------------

__global__ __launch_bounds__(256) void agg_logits(const float* __restrict__ G,
                                                  const int* __restrict__ row_ptr,
                                                  const int2* __restrict__ ev,
                                                  const float* __restrict__ bf,
                                                  float* __restrict__ out, int n) {
  const int wave = threadIdx.x >> 6;
  const int lane = threadIdx.x & 63;
  const int v = blockIdx.x * 4 + wave;
  if (v >= n) return;
  const int beg = row_ptr[v], end = row_ptr[v + 1];
  const int g = lane >> 4;           // 4 edge groups
  const int f = lane & 15;           // feature (class) index
  float acc = 0.f;
  int e = beg + g;
  for (; e + 4 < end; e += 8) {      // 2 edges per group per iter -> 8 gathers in flight
    int2 p0 = ev[e];
    int2 p1 = ev[e + 4];
    acc += __int_as_float(p0.y) * G[(size_t)p0.x * NCP + f]
         + __int_as_float(p1.y) * G[(size_t)p1.x * NCP + f];
  }
  for (; e < end; e += 4) {
    int2 p = ev[e];
    acc += __int_as_float(p.y) * G[(size_t)p.x * NCP + f];
  }
  acc += __shfl_xor(acc, 16);
  acc += __shfl_xor(acc, 32);
  float logit = acc + bf[f];
  float pv = (f < NCLS) ? logit : -INFINITY;
  float m = pv;
  #pragma unroll
  for (int s = 8; s >= 1; s >>= 1) m = fmaxf(m, __shfl_xor(m, s));
  float ex = (f < NCLS) ? expf(logit - m) : 0.f;
  float ssum = ex;
  #pragma unroll
  for (int s = 8; s >= 1; s >>= 1) ssum += __shfl_xor(ssum, s);
  float lse = m + logf(ssum);
  if (g == 0 && f < NCLS) out[(size_t)v * NCLS + f] = logit - lse;
}

// ---------------- launcher ----------------

extern "C" void kernel_launch(void* const* d_in, const int* in_sizes, int n_in,
                              void* d_out, int out_size, void* d_ws, size_t ws_size,
                              hipStream_t stream) {
  const float* x  = (const float*)d_in[0];
  const int*   ei = (const int*)d_in[1];
  const float* W1 = (const float*)d_in[2];
  const float* b1 = (const float*)d_in[3];
  const float* W2 = (const float*)d_in[4];
  const float* b2 = (const float*)d_in[5];
  const float* W3 = (const float*)d_in[6];
  const float* b3 = (const float*)d_in[7];
  const float* Wl = (const float*)d_in[8];
  const float* bl = (const float*)d_in[9];
  float* out = (float*)d_out;

  const int nN = in_sizes[0] / NFEAT;   // 100000
  const int nE = in_sizes[1] / 2;       // 1600000
  const int total = nN + nE;
  const int nb1024 = (nN + 1023) / 1024;

  char* ws = (char*)d_ws;
  int*   deg     = (int*)ws;     ws += alignup((size_t)nN * 4);
  float* dis     = (float*)ws;   ws += alignup((size_t)nN * 4);
  int*   row_ptr = (int*)ws;     ws += alignup((size_t)(nN + 1) * 4);
  int*   cnt     = (int*)ws;     ws += alignup((size_t)nN * 4);
  int*   bsums   = (int*)ws;     ws += alignup((size_t)nb1024 * 4);
  float* Wf      = (float*)ws;   ws += alignup((size_t)NFEAT * NCP * 4);
  float* bf      = (float*)ws;   ws += alignup((size_t)NCP * 4);
  int2*  ev      = (int2*)ws;    ws += alignup((size_t)total * 8);
  float* bufA    = (float*)ws;   ws += alignup((size_t)nN * NFEAT * 4);
  float* bufB    = (float*)ws;   ws += alignup((size_t)nN * NFEAT * 4);
  float* G       = bufB;         // alias: bufB is free during layer 3

  const int nb256 = (nN + 255) / 256;
  init_kernel<<<nb256, 256, 0, stream>>>(deg, cnt, nN);
  count_deg<<<1024, 256, 0, stream>>>(ei + nE, deg, nE);
  compute_dis<<<nb256, 256, 0, stream>>>(deg, dis, nN);
  scan_block<<<nb1024, 1024, 0, stream>>>(deg, row_ptr, bsums, nN);
  scan_sums<<<1, 1024, 0, stream>>>(bsums, row_ptr, nb1024, nN);
  scan_add<<<nb256, 256, 0, stream>>>(row_ptr, bsums, nN);
  fill_csr<<<2048, 256, 0, stream>>>(ei, dis, row_ptr, cnt, ev, nE, total);
  fold_weights<<<8, 256, 0, stream>>>(W3, Wl, b3, bl, Wf, bf);

  const int gemm_grid = (nN + BM - 1) / BM;
  const int node_grid = (nN + 3) / 4;

  // layer 1
  gemm128<<<gemm_grid, 256, 0, stream>>>(x, W1, bufB, nN);
  aggregate<<<node_grid, 256, 0, stream>>>(bufB, row_ptr, ev, b1, bufA, 1, nN);
  // layer 2
  gemm128<<<gemm_grid, 256, 0, stream>>>(bufA, W2, bufB, nN);
  aggregate<<<node_grid, 256, 0, stream>>>(bufB, row_ptr, ev, b2, bufA, 1, nN);
  // layer 3 folded with classifier: logits = Agg(H2 @ (W3@Wl)) + (b3@Wl + bl)
  gemm_small<<<(nN + 255) / 256, 256, 0, stream>>>(bufA, Wf, G, nN);
  agg_logits<<<node_grid, 256, 0, stream>>>(G, row_ptr, ev, bf, out, nN);
}

// Round 4
// 484.407 us; speedup vs baseline: 2.1655x; 1.1698x over previous
//
#include <hip/hip_runtime.h>

#define NFEAT 128
#define NCLS  10
#define NCP   16   // padded class count (alignment)

static inline size_t alignup(size_t x) { return (x + 255) & ~size_t(255); }

// bf16 helpers (bit-level, RNE) — avoids header API differences
__device__ __forceinline__ ushort f2bf(float f) {
  uint x = __float_as_uint(f);
  return (ushort)((x + 0x7fffu + ((x >> 16) & 1u)) >> 16);
}
__device__ __forceinline__ float bf2f(ushort u) {
  return __uint_as_float(((uint)u) << 16);
}

// ---------------- precompute kernels ----------------

__global__ void init_kernel(int* __restrict__ deg, int* __restrict__ cnt, int n) {
  int i = blockIdx.x * blockDim.x + threadIdx.x;
  if (i < n) { deg[i] = 1; cnt[i] = 0; }   // deg=1 accounts for the self-loop
}

__global__ void count_deg(const int* __restrict__ dst, int* __restrict__ deg, int e) {
  int i = blockIdx.x * blockDim.x + threadIdx.x;
  int stride = gridDim.x * blockDim.x;
  for (; i < e; i += stride) atomicAdd(&deg[dst[i]], 1);
}

__global__ void compute_dis(const int* __restrict__ deg, float* __restrict__ dis, int n) {
  int i = blockIdx.x * blockDim.x + threadIdx.x;
  if (i < n) dis[i] = rsqrtf((float)deg[i]);
}

// hierarchical scan: per-block scan + block-sums scan + offset add
__global__ __launch_bounds__(1024) void scan_block(const int* __restrict__ deg,
                                                   int* __restrict__ row_ptr,
                                                   int* __restrict__ block_sums, int n) {
  __shared__ int sbuf[1024];
  const int t = threadIdx.x;
  const int base = blockIdx.x * 1024;
  int x = (base + t < n) ? deg[base + t] : 0;
  sbuf[t] = x;
  __syncthreads();
  for (int off = 1; off < 1024; off <<= 1) {
    int v = (t >= off) ? sbuf[t - off] : 0;
    __syncthreads();
    sbuf[t] += v;
    __syncthreads();
  }
  if (base + t < n) row_ptr[base + t] = sbuf[t] - x;   // block-local exclusive
  if (t == 1023) block_sums[blockIdx.x] = sbuf[1023];
}

__global__ __launch_bounds__(1024) void scan_sums(int* __restrict__ block_sums,
                                                  int* __restrict__ row_ptr,
                                                  int nb, int n) {
  __shared__ int sbuf[1024];
  const int t = threadIdx.x;
  int x = (t < nb) ? block_sums[t] : 0;
  sbuf[t] = x;
  __syncthreads();
  for (int off = 1; off < 1024; off <<= 1) {
    int v = (t >= off) ? sbuf[t - off] : 0;
    __syncthreads();
    sbuf[t] += v;
    __syncthreads();
  }
  if (t < nb) block_sums[t] = sbuf[t] - x;             // exclusive block offsets
  if (t == nb - 1) row_ptr[n] = sbuf[t];               // grand total
}

__global__ void scan_add(int* __restrict__ row_ptr, const int* __restrict__ block_sums, int n) {
  int i = blockIdx.x * blockDim.x + threadIdx.x;
  if (i < n) row_ptr[i] += block_sums[i >> 10];
}

// counting-sort fill: items [0,E) are edges, [E, E+N) are self-loops
__global__ void fill_csr(const int* __restrict__ ei, const float* __restrict__ dis,
                         const int* __restrict__ row_ptr, int* __restrict__ cnt,
                         int2* __restrict__ ev, int nE, int total) {
  int i = blockIdx.x * blockDim.x + threadIdx.x;
  int stride = gridDim.x * blockDim.x;
  for (; i < total; i += stride) {
    int s, d;
    if (i < nE) { s = ei[i]; d = ei[nE + i]; }
    else        { s = i - nE; d = s; }
    int pos = atomicAdd(&cnt[d], 1);
    int idx = row_ptr[d] + pos;
    float v = dis[s] * dis[d];
    ev[idx] = make_int2(s, __float_as_int(v));
  }
}

// fold W3@Wl -> Wf[128x16], b3@Wl + bl -> bf[16]
__global__ __launch_bounds__(256) void fold_weights(const float* __restrict__ W3,
                                                    const float* __restrict__ Wl,
                                                    const float* __restrict__ b3,
                                                    const float* __restrict__ bl,
                                                    float* __restrict__ Wf,
                                                    float* __restrict__ bf) {
  int t = blockIdx.x * blockDim.x + threadIdx.x;
  if (t < NFEAT * NCP) {
    int r = t >> 4, c = t & 15;
    float s = 0.f;
    if (c < NCLS) {
      for (int k = 0; k < NFEAT; ++k) s += W3[r * NFEAT + k] * Wl[k * NCLS + c];
    }
    Wf[t] = s;
  }
  if (t < NCP) {
    float s = 0.f;
    if (t < NCLS) {
      s = bl[t];
      for (int k = 0; k < NFEAT; ++k) s += b3[k] * Wl[k * NCLS + t];
    }
    bf[t] = s;
  }
}

// ---------------- dense GEMM: Cb[nrows x 128](bf16) = A[nrows x 128] @ W[128 x 128] --------

#define BM 128
#define BN 128
#define BK 32

__global__ __launch_bounds__(256) void gemm128(const float* __restrict__ A,
                                               const float* __restrict__ W,
                                               ushort* __restrict__ Cb, int nrows) {
  __shared__ float As[BK][BM + 4];   // transposed A tile: As[k][m]
  __shared__ float Ws[BK][BN + 4];
  const int tid = threadIdx.x;
  const int row0 = blockIdx.x * BM;
  const int tx = tid & 15;           // 16 col-groups
  const int ty = tid >> 4;           // 16 row-groups
  float acc[8][8];
  #pragma unroll
  for (int i = 0; i < 8; ++i)
    #pragma unroll
    for (int j = 0; j < 8; ++j) acc[i][j] = 0.f;

  for (int k0 = 0; k0 < NFEAT; k0 += BK) {
    #pragma unroll
    for (int i = 0; i < 4; ++i) {
      int r = (tid >> 3) + i * 32;        // 0..127
      int c = (tid & 7) * 4;              // 0..28
      float4 a = make_float4(0.f, 0.f, 0.f, 0.f);
      if (row0 + r < nrows)
        a = *(const float4*)&A[(size_t)(row0 + r) * NFEAT + k0 + c];
      As[c + 0][r] = a.x; As[c + 1][r] = a.y; As[c + 2][r] = a.z; As[c + 3][r] = a.w;
    }
    #pragma unroll
    for (int i = 0; i < 4; ++i) {
      int kk = (tid >> 5) + i * 8;        // 0..31
      int c = (tid & 31) * 4;             // 0..124
      *(float4*)&Ws[kk][c] = *(const float4*)&W[(size_t)(k0 + kk) * BN + c];
    }
    __syncthreads();
    #pragma unroll 4
    for (int kk = 0; kk < BK; ++kk) {
      float4 a0 = *(const float4*)&As[kk][ty * 8];
      float4 a1 = *(const float4*)&As[kk][ty * 8 + 4];
      float4 w0 = *(const float4*)&Ws[kk][tx * 8];
      float4 w1 = *(const float4*)&Ws[kk][tx * 8 + 4];
      float a[8] = {a0.x, a0.y, a0.z, a0.w, a1.x, a1.y, a1.z, a1.w};
      float w[8] = {w0.x, w0.y, w0.z, w0.w, w1.x, w1.y, w1.z, w1.w};
      #pragma unroll
      for (int i = 0; i < 8; ++i)
        #pragma unroll
        for (int j = 0; j < 8; ++j) acc[i][j] += a[i] * w[j];
    }
    __syncthreads();
  }
  #pragma unroll
  for (int i = 0; i < 8; ++i) {
    int r = row0 + ty * 8 + i;
    if (r < nrows) {
      union { ushort u[8]; int4 v; } pk;
      #pragma unroll
      for (int j = 0; j < 8; ++j) pk.u[j] = f2bf(acc[i][j]);
      *(int4*)&Cb[(size_t)r * BN + tx * 8] = pk.v;
    }
  }
}

// ------- sparse aggregation (128 feats, bf16 source): half-wave ushort4, 8 in flight -------

__global__ __launch_bounds__(256) void aggregate(const ushort* __restrict__ hw,
                                                 const int* __restrict__ row_ptr,
                                                 const int2* __restrict__ ev,
                                                 const float* __restrict__ bias,
                                                 float* __restrict__ out,
                                                 int relu, int n) {
  const int wave = threadIdx.x >> 6;
  const int lane = threadIdx.x & 63;
  const int v = blockIdx.x * 4 + wave;
  if (v >= n) return;
  const int beg = row_ptr[v], end = row_ptr[v + 1];
  const int half = lane >> 5;        // 0/1: edge parity handled by this half-wave
  const int hl = lane & 31;          // feature group: feats hl*4 .. hl*4+3
  float4 acc = make_float4(0.f, 0.f, 0.f, 0.f);
  int e = beg + half;
  for (; e + 6 < end; e += 8) {      // 4 edges per half per iter -> 8 gathers in flight
    int2 p0 = ev[e];
    int2 p1 = ev[e + 2];
    int2 p2 = ev[e + 4];
    int2 p3 = ev[e + 6];
    float w0 = __int_as_float(p0.y);
    float w1 = __int_as_float(p1.y);
    float w2 = __int_as_float(p2.y);
    float w3 = __int_as_float(p3.y);
    ushort4 q0 = *(const ushort4*)&hw[(size_t)p0.x * NFEAT + hl * 4];
    ushort4 q1 = *(const ushort4*)&hw[(size_t)p1.x * NFEAT + hl * 4];
    ushort4 q2 = *(const ushort4*)&hw[(size_t)p2.x * NFEAT + hl * 4];
    ushort4 q3 = *(const ushort4*)&hw[(size_t)p3.x * NFEAT + hl * 4];
    acc.x += w0 * bf2f(q0.x) + w1 * bf2f(q1.x) + w2 * bf2f(q2.x) + w3 * bf2f(q3.x);
    acc.y += w0 * bf2f(q0.y) + w1 * bf2f(q1.y) + w2 * bf2f(q2.y) + w3 * bf2f(q3.y);
    acc.z += w0 * bf2f(q0.z) + w1 * bf2f(q1.z) + w2 * bf2f(q2.z) + w3 * bf2f(q3.z);
    acc.w += w0 * bf2f(q0.w) + w1 * bf2f(q1.w) + w2 * bf2f(q2.w) + w3 * bf2f(q3.w);
  }
  for (; e < end; e += 2) {
    int2 p = ev[e];
    float w = __int_as_float(p.y);
    ushort4 q = *(const ushort4*)&hw[(size_t)p.x * NFEAT + hl * 4];
    acc.x += w * bf2f(q.x); acc.y += w * bf2f(q.y);
    acc.z += w * bf2f(q.z); acc.w += w * bf2f(q.w);
  }
  acc.x += __shfl_xor(acc.x, 32);
  acc.y += __shfl_xor(acc.y, 32);
  acc.z += __shfl_xor(acc.z, 32);
  acc.w += __shfl_xor(acc.w, 32);
  if (half == 0) {
    float4 b = *(const float4*)&bias[hl * 4];
    acc.x += b.x; acc.y += b.y; acc.z += b.z; acc.w += b.w;
    if (relu) {
      acc.x = fmaxf(acc.x, 0.f); acc.y = fmaxf(acc.y, 0.f);
      acc.z = fmaxf(acc.z, 0.f); acc.w = fmaxf(acc.w, 0.f);
    }
    *(float4*)&out[(size_t)v * NFEAT + hl * 4] = acc;
  }
}

// ---------------- thin GEMM: G[N x 16] = A[N x 128] @ Wf[128 x 16] ----------------
// Thread-per-node: acc[16] in VGPRs, Wf read from LDS at wave-uniform addresses.

__global__ __launch_bounds__(256) void gemm_small(const float* __restrict__ A,
                                                  const float* __restrict__ Wf,
                                                  float* __restrict__ G, int n) {
  __shared__ float Ws[NFEAT * NCP];  // 8 KB
  for (int i = threadIdx.x; i < NFEAT * NCP; i += 256) Ws[i] = Wf[i];
  __syncthreads();
  const int v = blockIdx.x * 256 + threadIdx.x;
  if (v >= n) return;
  const float* Arow = A + (size_t)v * NFEAT;
  float acc[NCP];
  #pragma unroll
  for (int c = 0; c < NCP; ++c) acc[c] = 0.f;
  #pragma unroll 4
  for (int k = 0; k < NFEAT; k += 4) {
    float4 a = *(const float4*)&Arow[k];
    float av[4] = {a.x, a.y, a.z, a.w};
    #pragma unroll
    for (int j = 0; j < 4; ++j) {
      #pragma unroll
      for (int cq = 0; cq < NCP; cq += 4) {
        float4 w = *(const float4*)&Ws[(k + j) * NCP + cq];
        acc[cq + 0] += av[j] * w.x;
        acc[cq + 1] += av[j] * w.y;
        acc[cq + 2] += av[j] * w.z;
        acc[cq + 3] += av[j] * w.w;
      }
    }
  }
  #pragma unroll
  for (int cq = 0; cq < NCP; cq += 4)
    *(float4*)&G[(size_t)v * NCP + cq] =
        make_float4(acc[cq], acc[cq + 1], acc[cq + 2], acc[cq + 3]);
}

// ---------------- fused sparse aggregation (16 feats) + bias + log_softmax ----------------

__global__ __launch_bounds__(256) void agg_logits(const float* __restrict__ G,
                                                  const int* __restrict__ row_ptr,
                                                  const int2* __restrict__ ev,
                                                  const float* __restrict__ bf,
                                                  float* __restrict__ out, int n) {
  const int wave = threadIdx.x >> 6;
  const int lane = threadIdx.x & 63;
  const int v = blockIdx.x * 4 + wave;
  if (v >= n) return;
  const int beg = row_ptr[v], end = row_ptr[v + 1];
  const int g = lane >> 4;           // 4 edge groups
  const int f = lane & 15;           // feature (class) index
  float acc = 0.f;
  int e = beg + g;
  for (; e + 4 < end; e += 8) {      // 2 edges per group per iter -> 8 gathers in flight
    int2 p0 = ev[e];
    int2 p1 = ev[e + 4];
    acc += __int_as_float(p0.y) * G[(size_t)p0.x * NCP + f]
         + __int_as_float(p1.y) * G[(size_t)p1.x * NCP + f];
  }
  for (; e < end; e += 4) {
    int2 p = ev[e];
    acc += __int_as_float(p.y) * G[(size_t)p.x * NCP + f];
  }
  acc += __shfl_xor(acc, 16);
  acc += __shfl_xor(acc, 32);
  float logit = acc + bf[f];
  float pv = (f < NCLS) ? logit : -INFINITY;
  float m = pv;
  #pragma unroll
  for (int s = 8; s >= 1; s >>= 1) m = fmaxf(m, __shfl_xor(m, s));
  float ex = (f < NCLS) ? expf(logit - m) : 0.f;
  float ssum = ex;
  #pragma unroll
  for (int s = 8; s >= 1; s >>= 1) ssum += __shfl_xor(ssum, s);
  float lse = m + logf(ssum);
  if (g == 0 && f < NCLS) out[(size_t)v * NCLS + f] = logit - lse;
}

// ---------------- launcher ----------------

extern "C" void kernel_launch(void* const* d_in, const int* in_sizes, int n_in,
                              void* d_out, int out_size, void* d_ws, size_t ws_size,
                              hipStream_t stream) {
  const float* x  = (const float*)d_in[0];
  const int*   ei = (const int*)d_in[1];
  const float* W1 = (const float*)d_in[2];
  const float* b1 = (const float*)d_in[3];
  const float* W2 = (const float*)d_in[4];
  const float* b2 = (const float*)d_in[5];
  const float* W3 = (const float*)d_in[6];
  const float* b3 = (const float*)d_in[7];
  const float* Wl = (const float*)d_in[8];
  const float* bl = (const float*)d_in[9];
  float* out = (float*)d_out;

  const int nN = in_sizes[0] / NFEAT;   // 100000
  const int nE = in_sizes[1] / 2;       // 1600000
  const int total = nN + nE;
  const int nb1024 = (nN + 1023) / 1024;

  char* ws = (char*)d_ws;
  int*    deg     = (int*)ws;     ws += alignup((size_t)nN * 4);
  float*  dis     = (float*)ws;   ws += alignup((size_t)nN * 4);
  int*    row_ptr = (int*)ws;     ws += alignup((size_t)(nN + 1) * 4);
  int*    cnt     = (int*)ws;     ws += alignup((size_t)nN * 4);
  int*    bsums   = (int*)ws;     ws += alignup((size_t)nb1024 * 4);
  float*  Wf      = (float*)ws;   ws += alignup((size_t)NFEAT * NCP * 4);
  float*  bf      = (float*)ws;   ws += alignup((size_t)NCP * 4);
  int2*   ev      = (int2*)ws;    ws += alignup((size_t)total * 8);
  ushort* hb      = (ushort*)ws;  ws += alignup((size_t)nN * NFEAT * 2);  // bf16 gather buffer
  float*  bufA    = (float*)ws;   ws += alignup((size_t)nN * NFEAT * 4);
  float*  G       = (float*)ws;   ws += alignup((size_t)nN * NCP * 4);

  const int nb256 = (nN + 255) / 256;
  init_kernel<<<nb256, 256, 0, stream>>>(deg, cnt, nN);
  count_deg<<<1024, 256, 0, stream>>>(ei + nE, deg, nE);
  compute_dis<<<nb256, 256, 0, stream>>>(deg, dis, nN);
  scan_block<<<nb1024, 1024, 0, stream>>>(deg, row_ptr, bsums, nN);
  scan_sums<<<1, 1024, 0, stream>>>(bsums, row_ptr, nb1024, nN);
  scan_add<<<nb256, 256, 0, stream>>>(row_ptr, bsums, nN);
  fill_csr<<<2048, 256, 0, stream>>>(ei, dis, row_ptr, cnt, ev, nE, total);
  fold_weights<<<8, 256, 0, stream>>>(W3, Wl, b3, bl, Wf, bf);

  const int gemm_grid = (nN + BM - 1) / BM;
  const int node_grid = (nN + 3) / 4;

  // layer 1
  gemm128<<<gemm_grid, 256, 0, stream>>>(x, W1, hb, nN);
  aggregate<<<node_grid, 256, 0, stream>>>(hb, row_ptr, ev, b1, bufA, 1, nN);
  // layer 2
  gemm128<<<gemm_grid, 256, 0, stream>>>(bufA, W2, hb, nN);
  aggregate<<<node_grid, 256, 0, stream>>>(hb, row_ptr, ev, b2, bufA, 1, nN);
  // layer 3 folded with classifier: logits = Agg(H2 @ (W3@Wl)) + (b3@Wl + bl)
  gemm_small<<<(nN + 255) / 256, 256, 0, stream>>>(bufA, Wf, G, nN);
  agg_logits<<<node_grid, 256, 0, stream>>>(G, row_ptr, ev, bf, out, nN);
}

// Round 5
// 462.491 us; speedup vs baseline: 2.2681x; 1.0474x over previous
//
#include <hip/hip_runtime.h>

#define NFEAT 128
#define NCLS  10
#define NCP   16   // padded class count (alignment)

static inline size_t alignup(size_t x) { return (x + 255) & ~size_t(255); }

// bf16 helpers (bit-level, RNE)
__device__ __forceinline__ ushort f2bf(float f) {
  uint x = __float_as_uint(f);
  return (ushort)((x + 0x7fffu + ((x >> 16) & 1u)) >> 16);
}
__device__ __forceinline__ float bf2f(ushort u) {
  return __uint_as_float(((uint)u) << 16);
}

typedef short bf16x8 __attribute__((ext_vector_type(8)));
typedef float f32x4 __attribute__((ext_vector_type(4)));

// ---------------- precompute kernels ----------------

__global__ void init_kernel(int* __restrict__ deg, int* __restrict__ cnt, int n) {
  int i = blockIdx.x * blockDim.x + threadIdx.x;
  if (i < n) { deg[i] = 1; cnt[i] = 0; }   // deg=1 accounts for the self-loop
}

__global__ void count_deg(const int* __restrict__ dst, int* __restrict__ deg, int e) {
  int i = blockIdx.x * blockDim.x + threadIdx.x;
  int stride = gridDim.x * blockDim.x;
  for (; i < e; i += stride) atomicAdd(&deg[dst[i]], 1);
}

__global__ void compute_dis(const int* __restrict__ deg, float* __restrict__ dis, int n) {
  int i = blockIdx.x * blockDim.x + threadIdx.x;
  if (i < n) dis[i] = rsqrtf((float)deg[i]);
}

// hierarchical scan: per-block scan + block-sums scan + offset add
__global__ __launch_bounds__(1024) void scan_block(const int* __restrict__ deg,
                                                   int* __restrict__ row_ptr,
                                                   int* __restrict__ block_sums, int n) {
  __shared__ int sbuf[1024];
  const int t = threadIdx.x;
  const int base = blockIdx.x * 1024;
  int x = (base + t < n) ? deg[base + t] : 0;
  sbuf[t] = x;
  __syncthreads();
  for (int off = 1; off < 1024; off <<= 1) {
    int v = (t >= off) ? sbuf[t - off] : 0;
    __syncthreads();
    sbuf[t] += v;
    __syncthreads();
  }
  if (base + t < n) row_ptr[base + t] = sbuf[t] - x;   // block-local exclusive
  if (t == 1023) block_sums[blockIdx.x] = sbuf[1023];
}

__global__ __launch_bounds__(1024) void scan_sums(int* __restrict__ block_sums,
                                                  int* __restrict__ row_ptr,
                                                  int nb, int n) {
  __shared__ int sbuf[1024];
  const int t = threadIdx.x;
  int x = (t < nb) ? block_sums[t] : 0;
  sbuf[t] = x;
  __syncthreads();
  for (int off = 1; off < 1024; off <<= 1) {
    int v = (t >= off) ? sbuf[t - off] : 0;
    __syncthreads();
    sbuf[t] += v;
    __syncthreads();
  }
  if (t < nb) block_sums[t] = sbuf[t] - x;             // exclusive block offsets
  if (t == nb - 1) row_ptr[n] = sbuf[t];               // grand total
}

__global__ void scan_add(int* __restrict__ row_ptr, const int* __restrict__ block_sums, int n) {
  int i = blockIdx.x * blockDim.x + threadIdx.x;
  if (i < n) row_ptr[i] += block_sums[i >> 10];
}

// counting-sort fill: items [0,E) are edges, [E, E+N) are self-loops
__global__ void fill_csr(const int* __restrict__ ei, const float* __restrict__ dis,
                         const int* __restrict__ row_ptr, int* __restrict__ cnt,
                         int2* __restrict__ ev, int nE, int total) {
  int i = blockIdx.x * blockDim.x + threadIdx.x;
  int stride = gridDim.x * blockDim.x;
  for (; i < total; i += stride) {
    int s, d;
    if (i < nE) { s = ei[i]; d = ei[nE + i]; }
    else        { s = i - nE; d = s; }
    int pos = atomicAdd(&cnt[d], 1);
    int idx = row_ptr[d] + pos;
    float v = dis[s] * dis[d];
    ev[idx] = make_int2(s, __float_as_int(v));
  }
}

// fold W3@Wl -> Wf[128x16], b3@Wl + bl -> bf[16]
__global__ __launch_bounds__(256) void fold_weights(const float* __restrict__ W3,
                                                    const float* __restrict__ Wl,
                                                    const float* __restrict__ b3,
                                                    const float* __restrict__ bl,
                                                    float* __restrict__ Wf,
                                                    float* __restrict__ bf) {
  int t = blockIdx.x * blockDim.x + threadIdx.x;
  if (t < NFEAT * NCP) {
    int r = t >> 4, c = t & 15;
    float s = 0.f;
    if (c < NCLS) {
      for (int k = 0; k < NFEAT; ++k) s += W3[r * NFEAT + k] * Wl[k * NCLS + c];
    }
    Wf[t] = s;
  }
  if (t < NCP) {
    float s = 0.f;
    if (t < NCLS) {
      s = bl[t];
      for (int k = 0; k < NFEAT; ++k) s += b3[k] * Wl[k * NCLS + t];
    }
    bf[t] = s;
  }
}

// transpose + cast: Wt[n][k] (bf16) = W[k][n] (fp32)
__global__ __launch_bounds__(256) void prep_w(const float* __restrict__ W,
                                              ushort* __restrict__ Wt) {
  int t = blockIdx.x * 256 + threadIdx.x;
  if (t < NFEAT * NFEAT) {
    int n = t >> 7, k = t & 127;
    Wt[n * NFEAT + k] = f2bf(W[k * NFEAT + n]);
  }
}

// ---------------- MFMA GEMM: Cb[nrows x 128](bf16) = A[nrows x 128](fp32) @ W ----------------
// Wt is the pre-transposed bf16 weight [n][k]. BM=64 (4 waves x 16 rows), K=128 in 4 mfma
// k-steps, N=128 in 8 col-tiles. A staged in LDS as bf16 with XOR swizzle (G4) so the
// ds_read_b128 fragment reads are 2-way (free). B fragments read from L1/L2-hot Wt.

__global__ __launch_bounds__(256) void gemm_mfma(const float* __restrict__ A,
                                                 const ushort* __restrict__ Wt,
                                                 ushort* __restrict__ Cb, int nrows) {
  __shared__ __align__(16) ushort As[64 * NFEAT];   // 16 KB
  const int tid = threadIdx.x;
  const int row0 = blockIdx.x * 64;
  // ---- stage A (fp32 -> bf16, swizzled): thread = (row m = tid>>2, k-chunk (tid&3)*32)
  {
    const int m = tid >> 2;
    const int kc = (tid & 3) * 32;
    const int gr = row0 + m;
    float4 f[8];
    if (gr < nrows) {
      #pragma unroll
      for (int q = 0; q < 8; ++q)
        f[q] = *(const float4*)&A[(size_t)gr * NFEAT + kc + q * 4];
    } else {
      #pragma unroll
      for (int q = 0; q < 8; ++q) f[q] = make_float4(0.f, 0.f, 0.f, 0.f);
    }
    #pragma unroll
    for (int q = 0; q < 4; ++q) {          // 4 x 16B swizzled LDS writes
      union { ushort u[8]; int4 v; } pk;
      const float* fp = (const float*)&f[q * 2];
      #pragma unroll
      for (int j = 0; j < 8; ++j) pk.u[j] = f2bf(fp[j]);
      int byte = (m * 256 + (kc + q * 8) * 2) ^ ((m & 7) << 4);
      *(int4*)((char*)As + byte) = pk.v;
    }
  }
  __syncthreads();
  const int wave = tid >> 6;
  const int lane = tid & 63;
  const int m0 = wave * 16;
  // ---- A fragments: lane holds A[m0+(lane&15)][ks*32 + (lane>>4)*8 .. +7]
  bf16x8 afr[4];
  #pragma unroll
  for (int ks = 0; ks < 4; ++ks) {
    int m = m0 + (lane & 15);
    int kk = ks * 32 + (lane >> 4) * 8;
    int byte = (m * 256 + kk * 2) ^ ((m & 7) << 4);
    afr[ks] = *(const bf16x8*)((const char*)As + byte);
  }
  f32x4 acc[8];
  #pragma unroll
  for (int c = 0; c < 8; ++c) acc[c] = (f32x4){0.f, 0.f, 0.f, 0.f};
  // ---- main loop: 8 col-tiles x 4 k-steps; B frag: lane holds Wt[c*16+(lane&15)][kk..kk+7]
  #pragma unroll
  for (int c = 0; c < 8; ++c) {
    #pragma unroll
    for (int ks = 0; ks < 4; ++ks) {
      int n = c * 16 + (lane & 15);
      int kk = ks * 32 + (lane >> 4) * 8;
      bf16x8 bfr = *(const bf16x8*)&Wt[n * NFEAT + kk];
      acc[c] = __builtin_amdgcn_mfma_f32_16x16x32_bf16(afr[ks], bfr, acc[c], 0, 0, 0);
    }
  }
  // ---- epilogue: D[m][n], m = m0 + (lane>>4)*4 + r, n = c*16 + (lane&15)
  const int gr_base = row0 + m0 + (lane >> 4) * 4;
  #pragma unroll
  for (int c = 0; c < 8; ++c) {
    #pragma unroll
    for (int r = 0; r < 4; ++r) {
      int gr = gr_base + r;
      if (gr < nrows)
        Cb[(size_t)gr * NFEAT + c * 16 + (lane & 15)] = f2bf(acc[c][r]);
    }
  }
}

// ------- sparse aggregation (128 feats, bf16 source): half-wave ushort4, 8 in flight -------

__global__ __launch_bounds__(256) void aggregate(const ushort* __restrict__ hw,
                                                 const int* __restrict__ row_ptr,
                                                 const int2* __restrict__ ev,
                                                 const float* __restrict__ bias,
                                                 float* __restrict__ out,
                                                 int relu, int n) {
  const int wave = threadIdx.x >> 6;
  const int lane = threadIdx.x & 63;
  const int v = blockIdx.x * 4 + wave;
  if (v >= n) return;
  const int beg = row_ptr[v], end = row_ptr[v + 1];
  const int half = lane >> 5;        // 0/1: edge parity handled by this half-wave
  const int hl = lane & 31;          // feature group: feats hl*4 .. hl*4+3
  float4 acc = make_float4(0.f, 0.f, 0.f, 0.f);
  int e = beg + half;
  for (; e + 6 < end; e += 8) {      // 4 edges per half per iter -> 8 gathers in flight
    int2 p0 = ev[e];
    int2 p1 = ev[e + 2];
    int2 p2 = ev[e + 4];
    int2 p3 = ev[e + 6];
    float w0 = __int_as_float(p0.y);
    float w1 = __int_as_float(p1.y);
    float w2 = __int_as_float(p2.y);
    float w3 = __int_as_float(p3.y);
    ushort4 q0 = *(const ushort4*)&hw[(size_t)p0.x * NFEAT + hl * 4];
    ushort4 q1 = *(const ushort4*)&hw[(size_t)p1.x * NFEAT + hl * 4];
    ushort4 q2 = *(const ushort4*)&hw[(size_t)p2.x * NFEAT + hl * 4];
    ushort4 q3 = *(const ushort4*)&hw[(size_t)p3.x * NFEAT + hl * 4];
    acc.x += w0 * bf2f(q0.x) + w1 * bf2f(q1.x) + w2 * bf2f(q2.x) + w3 * bf2f(q3.x);
    acc.y += w0 * bf2f(q0.y) + w1 * bf2f(q1.y) + w2 * bf2f(q2.y) + w3 * bf2f(q3.y);
    acc.z += w0 * bf2f(q0.z) + w1 * bf2f(q1.z) + w2 * bf2f(q2.z) + w3 * bf2f(q3.z);
    acc.w += w0 * bf2f(q0.w) + w1 * bf2f(q1.w) + w2 * bf2f(q2.w) + w3 * bf2f(q3.w);
  }
  for (; e < end; e += 2) {
    int2 p = ev[e];
    float w = __int_as_float(p.y);
    ushort4 q = *(const ushort4*)&hw[(size_t)p.x * NFEAT + hl * 4];
    acc.x += w * bf2f(q.x); acc.y += w * bf2f(q.y);
    acc.z += w * bf2f(q.z); acc.w += w * bf2f(q.w);
  }
  acc.x += __shfl_xor(acc.x, 32);
  acc.y += __shfl_xor(acc.y, 32);
  acc.z += __shfl_xor(acc.z, 32);
  acc.w += __shfl_xor(acc.w, 32);
  if (half == 0) {
    float4 b = *(const float4*)&bias[hl * 4];
    acc.x += b.x; acc.y += b.y; acc.z += b.z; acc.w += b.w;
    if (relu) {
      acc.x = fmaxf(acc.x, 0.f); acc.y = fmaxf(acc.y, 0.f);
      acc.z = fmaxf(acc.z, 0.f); acc.w = fmaxf(acc.w, 0.f);
    }
    *(float4*)&out[(size_t)v * NFEAT + hl * 4] = acc;
  }
}

// ---------------- thin GEMM: G[N x 16] = A[N x 128] @ Wf[128 x 16] ----------------

__global__ __launch_bounds__(256) void gemm_small(const float* __restrict__ A,
                                                  const float* __restrict__ Wf,
                                                  float* __restrict__ G, int n) {
  __shared__ float Ws[NFEAT * NCP];  // 8 KB
  for (int i = threadIdx.x; i < NFEAT * NCP; i += 256) Ws[i] = Wf[i];
  __syncthreads();
  const int v = blockIdx.x * 256 + threadIdx.x;
  if (v >= n) return;
  const float* Arow = A + (size_t)v * NFEAT;
  float acc[NCP];
  #pragma unroll
  for (int c = 0; c < NCP; ++c) acc[c] = 0.f;
  #pragma unroll 4
  for (int k = 0; k < NFEAT; k += 4) {
    float4 a = *(const float4*)&Arow[k];
    float av[4] = {a.x, a.y, a.z, a.w};
    #pragma unroll
    for (int j = 0; j < 4; ++j) {
      #pragma unroll
      for (int cq = 0; cq < NCP; cq += 4) {
        float4 w = *(const float4*)&Ws[(k + j) * NCP + cq];
        acc[cq + 0] += av[j] * w.x;
        acc[cq + 1] += av[j] * w.y;
        acc[cq + 2] += av[j] * w.z;
        acc[cq + 3] += av[j] * w.w;
      }
    }
  }
  #pragma unroll
  for (int cq = 0; cq < NCP; cq += 4)
    *(float4*)&G[(size_t)v * NCP + cq] =
        make_float4(acc[cq], acc[cq + 1], acc[cq + 2], acc[cq + 3]);
}

// ---------------- fused sparse aggregation (16 feats) + bias + log_softmax ----------------

__global__ __launch_bounds__(256) void agg_logits(const float* __restrict__ G,
                                                  const int* __restrict__ row_ptr,
                                                  const int2* __restrict__ ev,
                                                  const float* __restrict__ bf,
                                                  float* __restrict__ out, int n) {
  const int wave = threadIdx.x >> 6;
  const int lane = threadIdx.x & 63;
  const int v = blockIdx.x * 4 + wave;
  if (v >= n) return;
  const int beg = row_ptr[v], end = row_ptr[v + 1];
  const int g = lane >> 4;           // 4 edge groups
  const int f = lane & 15;           // feature (class) index
  float acc = 0.f;
  int e = beg + g;
  for (; e + 4 < end; e += 8) {      // 2 edges per group per iter -> 8 gathers in flight
    int2 p0 = ev[e];
    int2 p1 = ev[e + 4];
    acc += __int_as_float(p0.y) * G[(size_t)p0.x * NCP + f]
         + __int_as_float(p1.y) * G[(size_t)p1.x * NCP + f];
  }
  for (; e < end; e += 4) {
    int2 p = ev[e];
    acc += __int_as_float(p.y) * G[(size_t)p.x * NCP + f];
  }
  acc += __shfl_xor(acc, 16);
  acc += __shfl_xor(acc, 32);
  float logit = acc + bf[f];
  float pv = (f < NCLS) ? logit : -INFINITY;
  float m = pv;
  #pragma unroll
  for (int s = 8; s >= 1; s >>= 1) m = fmaxf(m, __shfl_xor(m, s));
  float ex = (f < NCLS) ? expf(logit - m) : 0.f;
  float ssum = ex;
  #pragma unroll
  for (int s = 8; s >= 1; s >>= 1) ssum += __shfl_xor(ssum, s);
  float lse = m + logf(ssum);
  if (g == 0 && f < NCLS) out[(size_t)v * NCLS + f] = logit - lse;
}

// ---------------- launcher ----------------

extern "C" void kernel_launch(void* const* d_in, const int* in_sizes, int n_in,
                              void* d_out, int out_size, void* d_ws, size_t ws_size,
                              hipStream_t stream) {
  const float* x  = (const float*)d_in[0];
  const int*   ei = (const int*)d_in[1];
  const float* W1 = (const float*)d_in[2];
  const float* b1 = (const float*)d_in[3];
  const float* W2 = (const float*)d_in[4];
  const float* b2 = (const float*)d_in[5];
  const float* W3 = (const float*)d_in[6];
  const float* b3 = (const float*)d_in[7];
  const float* Wl = (const float*)d_in[8];
  const float* bl = (const float*)d_in[9];
  float* out = (float*)d_out;

  const int nN = in_sizes[0] / NFEAT;   // 100000
  const int nE = in_sizes[1] / 2;       // 1600000
  const int total = nN + nE;
  const int nb1024 = (nN + 1023) / 1024;

  char* ws = (char*)d_ws;
  int*    deg     = (int*)ws;     ws += alignup((size_t)nN * 4);
  float*  dis     = (float*)ws;   ws += alignup((size_t)nN * 4);
  int*    row_ptr = (int*)ws;     ws += alignup((size_t)(nN + 1) * 4);
  int*    cnt     = (int*)ws;     ws += alignup((size_t)nN * 4);
  int*    bsums   = (int*)ws;     ws += alignup((size_t)nb1024 * 4);
  float*  Wf      = (float*)ws;   ws += alignup((size_t)NFEAT * NCP * 4);
  float*  bf      = (float*)ws;   ws += alignup((size_t)NCP * 4);
  ushort* Wt1     = (ushort*)ws;  ws += alignup((size_t)NFEAT * NFEAT * 2);
  ushort* Wt2     = (ushort*)ws;  ws += alignup((size_t)NFEAT * NFEAT * 2);
  int2*   ev      = (int2*)ws;    ws += alignup((size_t)total * 8);
  ushort* hb      = (ushort*)ws;  ws += alignup((size_t)nN * NFEAT * 2);  // bf16 gather buffer
  float*  bufA    = (float*)ws;   ws += alignup((size_t)nN * NFEAT * 4);
  float*  G       = (float*)ws;   ws += alignup((size_t)nN * NCP * 4);

  const int nb256 = (nN + 255) / 256;
  init_kernel<<<nb256, 256, 0, stream>>>(deg, cnt, nN);
  count_deg<<<1024, 256, 0, stream>>>(ei + nE, deg, nE);
  compute_dis<<<nb256, 256, 0, stream>>>(deg, dis, nN);
  scan_block<<<nb1024, 1024, 0, stream>>>(deg, row_ptr, bsums, nN);
  scan_sums<<<1, 1024, 0, stream>>>(bsums, row_ptr, nb1024, nN);
  scan_add<<<nb256, 256, 0, stream>>>(row_ptr, bsums, nN);
  fill_csr<<<2048, 256, 0, stream>>>(ei, dis, row_ptr, cnt, ev, nE, total);
  fold_weights<<<8, 256, 0, stream>>>(W3, Wl, b3, bl, Wf, bf);
  prep_w<<<64, 256, 0, stream>>>(W1, Wt1);
  prep_w<<<64, 256, 0, stream>>>(W2, Wt2);

  const int gemm_grid = (nN + 63) / 64;
  const int node_grid = (nN + 3) / 4;

  // layer 1
  gemm_mfma<<<gemm_grid, 256, 0, stream>>>(x, Wt1, hb, nN);
  aggregate<<<node_grid, 256, 0, stream>>>(hb, row_ptr, ev, b1, bufA, 1, nN);
  // layer 2
  gemm_mfma<<<gemm_grid, 256, 0, stream>>>(bufA, Wt2, hb, nN);
  aggregate<<<node_grid, 256, 0, stream>>>(hb, row_ptr, ev, b2, bufA, 1, nN);
  // layer 3 folded with classifier: logits = Agg(H2 @ (W3@Wl)) + (b3@Wl + bl)
  gemm_small<<<(nN + 255) / 256, 256, 0, stream>>>(bufA, Wf, G, nN);
  agg_logits<<<node_grid, 256, 0, stream>>>(G, row_ptr, ev, bf, out, nN);
}

// Round 6
// 359.717 us; speedup vs baseline: 2.9162x; 1.2857x over previous
//
#include <hip/hip_runtime.h>

#define NFEAT 128
#define NCLS  10
#define NCP   16    // padded class count
#define BROW  512   // rows per bucket
#define BINC  4096  // items per binning chunk

static inline size_t alignup(size_t x) { return (x + 255) & ~size_t(255); }

// bf16 helpers (bit-level, RNE)
__device__ __forceinline__ ushort f2bf(float f) {
  uint x = __float_as_uint(f);
  return (ushort)((x + 0x7fffu + ((x >> 16) & 1u)) >> 16);
}
__device__ __forceinline__ float bf2f(ushort u) {
  return __uint_as_float(((uint)u) << 16);
}

typedef short bf16x8 __attribute__((ext_vector_type(8)));
typedef float f32x4 __attribute__((ext_vector_type(4)));

// ---------------- CSR build (bucketed, write-amplification-free) ----------------

__global__ void zero_ints(int* __restrict__ p, int n) {
  int i = blockIdx.x * 256 + threadIdx.x;
  if (i < n) p[i] = 0;
}

// per-block LDS histogram of dst buckets; one global atomic per (block,bucket)
__global__ __launch_bounds__(256) void bucket_hist(const int* __restrict__ dst,
                                                   int* __restrict__ bkt_cnt,
                                                   int e, int nbkt) {
  __shared__ int hist[256];
  for (int t = threadIdx.x; t < nbkt; t += 256) hist[t] = 0;
  __syncthreads();
  int i = blockIdx.x * 256 + threadIdx.x;
  int stride = gridDim.x * 256;
  for (; i < e; i += stride) atomicAdd(&hist[dst[i] >> 9], 1);
  __syncthreads();
  for (int t = threadIdx.x; t < nbkt; t += 256)
    if (hist[t]) atomicAdd(&bkt_cnt[t], hist[t]);
}

// scan bucket counts (+self-loop nodes per bucket) -> bkt_off, init gfrontier
__global__ __launch_bounds__(256) void bkt_scan(const int* __restrict__ bkt_cnt,
                                                int* __restrict__ bkt_off,
                                                int* __restrict__ gfrontier,
                                                int n, int nbkt) {
  __shared__ int sbuf[256];
  const int t = threadIdx.x;
  int x = 0;
  if (t < nbkt) {
    int lo = t << 9;
    int nodes = n - lo; if (nodes > BROW) nodes = BROW;
    x = bkt_cnt[t] + nodes;
  }
  sbuf[t] = x;
  __syncthreads();
  for (int off = 1; off < 256; off <<= 1) {
    int v = (t >= off) ? sbuf[t - off] : 0;
    __syncthreads();
    sbuf[t] += v;
    __syncthreads();
  }
  if (t < nbkt) { bkt_off[t] = sbuf[t] - x; gfrontier[t] = sbuf[t] - x; }
  if (t == nbkt - 1) bkt_off[nbkt] = sbuf[t];
}

// LDS-staged binning: items [0,E)=edges, [E,E+N)=self-loops; coalesced per-bucket bursts
__global__ __launch_bounds__(256) void bin_items(const int* __restrict__ ei,
                                                 int nE, int total, int nbkt,
                                                 int* __restrict__ gfrontier,
                                                 int2* __restrict__ binned) {
  __shared__ int hist[256];   // counts, then running local offsets
  __shared__ int loff[256];
  __shared__ int gbase[256];
  __shared__ int sbuf[256];
  __shared__ int2 st[BINC];
  const int t = threadIdx.x;
  const int chunk0 = blockIdx.x * BINC;
  for (int q = t; q < nbkt; q += 256) hist[q] = 0;
  __syncthreads();
  // phase A: local histogram
  for (int j = t; j < BINC; j += 256) {
    int i = chunk0 + j;
    if (i < total) {
      int d = (i < nE) ? ei[nE + i] : (i - nE);
      atomicAdd(&hist[d >> 9], 1);
    }
  }
  __syncthreads();
  // phase B: exclusive scan of hist -> loff; reserve global space per bucket
  int x = (t < nbkt) ? hist[t] : 0;
  sbuf[t] = x;
  __syncthreads();
  for (int off = 1; off < 256; off <<= 1) {
    int v = (t >= off) ? sbuf[t - off] : 0;
    __syncthreads();
    sbuf[t] += v;
    __syncthreads();
  }
  loff[t] = sbuf[t] - x;
  gbase[t] = (t < nbkt && x > 0) ? atomicAdd(&gfrontier[t], x) : 0;
  __syncthreads();
  hist[t] = loff[t];          // running local frontier
  __syncthreads();
  // phase C: stage items bucket-grouped in LDS
  for (int j = t; j < BINC; j += 256) {
    int i = chunk0 + j;
    if (i < total) {
      int s, d;
      if (i < nE) { s = ei[i]; d = ei[nE + i]; }
      else        { s = i - nE; d = s; }
      int p = atomicAdd(&hist[d >> 9], 1);
      st[p] = make_int2(s, d);
    }
  }
  __syncthreads();
  // phase D: linear sweep -> coalesced per-bucket global bursts
  int M = total - chunk0; if (M > BINC) M = BINC;
  for (int j = t; j < M; j += 256) {
    int2 it = st[j];
    int b = it.y >> 9;
    binned[gbase[b] + (j - loff[b])] = it;
  }
}

// per-bucket: deg hist -> dis + row_ptr (LDS scan), scatter ev (4B src) locally
__global__ __launch_bounds__(512) void bucket_finalize(const int2* __restrict__ binned,
                                                       const int* __restrict__ bkt_off,
                                                       int* __restrict__ row_ptr,
                                                       float* __restrict__ dis,
                                                       int* __restrict__ ev,
                                                       int n, int nbkt) {
  __shared__ int hist[BROW];
  __shared__ int sbuf[BROW];
  __shared__ int pre[BROW];
  __shared__ int front[BROW];
  const int b = blockIdx.x;
  const int t = threadIdx.x;
  const int row0 = b << 9;
  const int beg = bkt_off[b], end = bkt_off[b + 1];
  hist[t] = 0; front[t] = 0;
  __syncthreads();
  for (int j = beg + t; j < end; j += BROW)
    atomicAdd(&hist[binned[j].y - row0], 1);
  __syncthreads();
  const int x = hist[t];
  const int v = row0 + t;
  if (v < n) dis[v] = rsqrtf((float)x);
  sbuf[t] = x;
  __syncthreads();
  for (int off = 1; off < BROW; off <<= 1) {
    int val = (t >= off) ? sbuf[t - off] : 0;
    __syncthreads();
    sbuf[t] += val;
    __syncthreads();
  }
  pre[t] = sbuf[t] - x;
  if (v < n) row_ptr[v] = beg + pre[t];
  if (b == nbkt - 1 && t == 0) row_ptr[n] = end;
  __syncthreads();
  for (int j = beg + t; j < end; j += BROW) {
    int2 it = binned[j];
    int dl = it.y - row0;
    int slot = atomicAdd(&front[dl], 1);
    ev[beg + pre[dl] + slot] = it.x;
  }
}

// ---------------- weight prep ----------------

// fold W3@Wl -> Wf[128x16], b3@Wl + bl -> bf[16]
__global__ __launch_bounds__(256) void fold_weights(const float* __restrict__ W3,
                                                    const float* __restrict__ Wl,
                                                    const float* __restrict__ b3,
                                                    const float* __restrict__ bl,
                                                    float* __restrict__ Wf,
                                                    float* __restrict__ bf) {
  int t = blockIdx.x * blockDim.x + threadIdx.x;
  if (t < NFEAT * NCP) {
    int r = t >> 4, c = t & 15;
    float s = 0.f;
    if (c < NCLS) {
      for (int k = 0; k < NFEAT; ++k) s += W3[r * NFEAT + k] * Wl[k * NCLS + c];
    }
    Wf[t] = s;
  }
  if (t < NCP) {
    float s = 0.f;
    if (t < NCLS) {
      s = bl[t];
      for (int k = 0; k < NFEAT; ++k) s += b3[k] * Wl[k * NCLS + t];
    }
    bf[t] = s;
  }
}

// transpose + cast: Wt[n][k] (bf16) = W[k][n] (fp32)
__global__ __launch_bounds__(256) void prep_w(const float* __restrict__ W,
                                              ushort* __restrict__ Wt) {
  int t = blockIdx.x * 256 + threadIdx.x;
  if (t < NFEAT * NFEAT) {
    int n = t >> 7, k = t & 127;
    Wt[n * NFEAT + k] = f2bf(W[k * NFEAT + n]);
  }
}

// ---------------- MFMA GEMM: Cb[r] = bf16(dis[r] * (A[r] @ W)) ----------------

__global__ __launch_bounds__(256) void gemm_mfma(const float* __restrict__ A,
                                                 const ushort* __restrict__ Wt,
                                                 const float* __restrict__ dis,
                                                 ushort* __restrict__ Cb, int nrows) {
  __shared__ __align__(16) ushort As[64 * NFEAT];   // 16 KB
  const int tid = threadIdx.x;
  const int row0 = blockIdx.x * 64;
  {
    const int m = tid >> 2;
    const int kc = (tid & 3) * 32;
    const int gr = row0 + m;
    float4 f[8];
    if (gr < nrows) {
      #pragma unroll
      for (int q = 0; q < 8; ++q)
        f[q] = *(const float4*)&A[(size_t)gr * NFEAT + kc + q * 4];
    } else {
      #pragma unroll
      for (int q = 0; q < 8; ++q) f[q] = make_float4(0.f, 0.f, 0.f, 0.f);
    }
    #pragma unroll
    for (int q = 0; q < 4; ++q) {
      union { ushort u[8]; int4 v; } pk;
      const float* fp = (const float*)&f[q * 2];
      #pragma unroll
      for (int j = 0; j < 8; ++j) pk.u[j] = f2bf(fp[j]);
      int byte = (m * 256 + (kc + q * 8) * 2) ^ ((m & 7) << 4);
      *(int4*)((char*)As + byte) = pk.v;
    }
  }
  __syncthreads();
  const int wave = tid >> 6;
  const int lane = tid & 63;
  const int m0 = wave * 16;
  bf16x8 afr[4];
  #pragma unroll
  for (int ks = 0; ks < 4; ++ks) {
    int m = m0 + (lane & 15);
    int kk = ks * 32 + (lane >> 4) * 8;
    int byte = (m * 256 + kk * 2) ^ ((m & 7) << 4);
    afr[ks] = *(const bf16x8*)((const char*)As + byte);
  }
  f32x4 acc[8];
  #pragma unroll
  for (int c = 0; c < 8; ++c) acc[c] = (f32x4){0.f, 0.f, 0.f, 0.f};
  #pragma unroll
  for (int c = 0; c < 8; ++c) {
    #pragma unroll
    for (int ks = 0; ks < 4; ++ks) {
      int n = c * 16 + (lane & 15);
      int kk = ks * 32 + (lane >> 4) * 8;
      bf16x8 bfr = *(const bf16x8*)&Wt[n * NFEAT + kk];
      acc[c] = __builtin_amdgcn_mfma_f32_16x16x32_bf16(afr[ks], bfr, acc[c], 0, 0, 0);
    }
  }
  const int gr_base = row0 + m0 + (lane >> 4) * 4;
  float dr[4];
  #pragma unroll
  for (int r = 0; r < 4; ++r)
    dr[r] = (gr_base + r < nrows) ? dis[gr_base + r] : 0.f;
  #pragma unroll
  for (int c = 0; c < 8; ++c) {
    #pragma unroll
    for (int r = 0; r < 4; ++r) {
      int gr = gr_base + r;
      if (gr < nrows)
        Cb[(size_t)gr * NFEAT + c * 16 + (lane & 15)] = f2bf(acc[c][r] * dr[r]);
    }
  }
}

// ------- sparse aggregation: out[v] = relu?(dis[v]*Σ h'[src] + bias) -------

__global__ __launch_bounds__(256) void aggregate(const ushort* __restrict__ hw,
                                                 const int* __restrict__ row_ptr,
                                                 const int* __restrict__ ev,
                                                 const float* __restrict__ dis,
                                                 const float* __restrict__ bias,
                                                 float* __restrict__ out,
                                                 int relu, int n) {
  const int wave = threadIdx.x >> 6;
  const int lane = threadIdx.x & 63;
  const int v = blockIdx.x * 4 + wave;
  if (v >= n) return;
  const int beg = row_ptr[v], end = row_ptr[v + 1];
  const int half = lane >> 5;        // 0/1: edge parity handled by this half-wave
  const int hl = lane & 31;          // feature group: feats hl*4 .. hl*4+3
  float4 acc = make_float4(0.f, 0.f, 0.f, 0.f);
  int e = beg + half;
  for (; e + 6 < end; e += 8) {      // 4 edges per half per iter -> 8 gathers in flight
    int s0 = ev[e];
    int s1 = ev[e + 2];
    int s2 = ev[e + 4];
    int s3 = ev[e + 6];
    ushort4 q0 = *(const ushort4*)&hw[(size_t)s0 * NFEAT + hl * 4];
    ushort4 q1 = *(const ushort4*)&hw[(size_t)s1 * NFEAT + hl * 4];
    ushort4 q2 = *(const ushort4*)&hw[(size_t)s2 * NFEAT + hl * 4];
    ushort4 q3 = *(const ushort4*)&hw[(size_t)s3 * NFEAT + hl * 4];
    acc.x += bf2f(q0.x) + bf2f(q1.x) + bf2f(q2.x) + bf2f(q3.x);
    acc.y += bf2f(q0.y) + bf2f(q1.y) + bf2f(q2.y) + bf2f(q3.y);
    acc.z += bf2f(q0.z) + bf2f(q1.z) + bf2f(q2.z) + bf2f(q3.z);
    acc.w += bf2f(q0.w) + bf2f(q1.w) + bf2f(q2.w) + bf2f(q3.w);
  }
  for (; e < end; e += 2) {
    int s = ev[e];
    ushort4 q = *(const ushort4*)&hw[(size_t)s * NFEAT + hl * 4];
    acc.x += bf2f(q.x); acc.y += bf2f(q.y);
    acc.z += bf2f(q.z); acc.w += bf2f(q.w);
  }
  acc.x += __shfl_xor(acc.x, 32);
  acc.y += __shfl_xor(acc.y, 32);
  acc.z += __shfl_xor(acc.z, 32);
  acc.w += __shfl_xor(acc.w, 32);
  if (half == 0) {
    float dv = dis[v];
    float4 b = *(const float4*)&bias[hl * 4];
    acc.x = acc.x * dv + b.x; acc.y = acc.y * dv + b.y;
    acc.z = acc.z * dv + b.z; acc.w = acc.w * dv + b.w;
    if (relu) {
      acc.x = fmaxf(acc.x, 0.f); acc.y = fmaxf(acc.y, 0.f);
      acc.z = fmaxf(acc.z, 0.f); acc.w = fmaxf(acc.w, 0.f);
    }
    *(float4*)&out[(size_t)v * NFEAT + hl * 4] = acc;
  }
}

// ---------------- thin GEMM: G[v] = dis[v] * (A[v] @ Wf) ----------------

__global__ __launch_bounds__(256) void gemm_small(const float* __restrict__ A,
                                                  const float* __restrict__ Wf,
                                                  const float* __restrict__ dis,
                                                  float* __restrict__ G, int n) {
  __shared__ float Ws[NFEAT * NCP];  // 8 KB
  for (int i = threadIdx.x; i < NFEAT * NCP; i += 256) Ws[i] = Wf[i];
  __syncthreads();
  const int v = blockIdx.x * 256 + threadIdx.x;
  if (v >= n) return;
  const float* Arow = A + (size_t)v * NFEAT;
  float acc[NCP];
  #pragma unroll
  for (int c = 0; c < NCP; ++c) acc[c] = 0.f;
  #pragma unroll 4
  for (int k = 0; k < NFEAT; k += 4) {
    float4 a = *(const float4*)&Arow[k];
    float av[4] = {a.x, a.y, a.z, a.w};
    #pragma unroll
    for (int j = 0; j < 4; ++j) {
      #pragma unroll
      for (int cq = 0; cq < NCP; cq += 4) {
        float4 w = *(const float4*)&Ws[(k + j) * NCP + cq];
        acc[cq + 0] += av[j] * w.x;
        acc[cq + 1] += av[j] * w.y;
        acc[cq + 2] += av[j] * w.z;
        acc[cq + 3] += av[j] * w.w;
      }
    }
  }
  const float dv = dis[v];
  #pragma unroll
  for (int cq = 0; cq < NCP; cq += 4)
    *(float4*)&G[(size_t)v * NCP + cq] =
        make_float4(acc[cq] * dv, acc[cq + 1] * dv, acc[cq + 2] * dv, acc[cq + 3] * dv);
}

// ---------------- fused aggregation (16 feats) + bias + log_softmax ----------------

__global__ __launch_bounds__(256) void agg_logits(const float* __restrict__ G,
                                                  const int* __restrict__ row_ptr,
                                                  const int* __restrict__ ev,
                                                  const float* __restrict__ dis,
                                                  const float* __restrict__ bf,
                                                  float* __restrict__ out, int n) {
  const int wave = threadIdx.x >> 6;
  const int lane = threadIdx.x & 63;
  const int v = blockIdx.x * 4 + wave;
  if (v >= n) return;
  const int beg = row_ptr[v], end = row_ptr[v + 1];
  const int g = lane >> 4;           // 4 edge groups
  const int f = lane & 15;           // feature (class) index
  float acc = 0.f;
  int e = beg + g;
  for (; e + 4 < end; e += 8) {      // 2 edges per group per iter -> 8 gathers in flight
    int s0 = ev[e];
    int s1 = ev[e + 4];
    acc += G[(size_t)s0 * NCP + f] + G[(size_t)s1 * NCP + f];
  }
  for (; e < end; e += 4) {
    acc += G[(size_t)ev[e] * NCP + f];
  }
  acc += __shfl_xor(acc, 16);
  acc += __shfl_xor(acc, 32);
  float logit = dis[v] * acc + bf[f];
  float pv = (f < NCLS) ? logit : -INFINITY;
  float m = pv;
  #pragma unroll
  for (int s = 8; s >= 1; s >>= 1) m = fmaxf(m, __shfl_xor(m, s));
  float ex = (f < NCLS) ? expf(logit - m) : 0.f;
  float ssum = ex;
  #pragma unroll
  for (int s = 8; s >= 1; s >>= 1) ssum += __shfl_xor(ssum, s);
  float lse = m + logf(ssum);
  if (g == 0 && f < NCLS) out[(size_t)v * NCLS + f] = logit - lse;
}

// ---------------- launcher ----------------

extern "C" void kernel_launch(void* const* d_in, const int* in_sizes, int n_in,
                              void* d_out, int out_size, void* d_ws, size_t ws_size,
                              hipStream_t stream) {
  const float* x  = (const float*)d_in[0];
  const int*   ei = (const int*)d_in[1];
  const float* W1 = (const float*)d_in[2];
  const float* b1 = (const float*)d_in[3];
  const float* W2 = (const float*)d_in[4];
  const float* b2 = (const float*)d_in[5];
  const float* W3 = (const float*)d_in[6];
  const float* b3 = (const float*)d_in[7];
  const float* Wl = (const float*)d_in[8];
  const float* bl = (const float*)d_in[9];
  float* out = (float*)d_out;

  const int nN = in_sizes[0] / NFEAT;   // 100000
  const int nE = in_sizes[1] / 2;       // 1600000
  const int total = nN + nE;
  const int nbkt = (nN + BROW - 1) >> 9;          // 196
  const int nbBin = (total + BINC - 1) / BINC;    // 416

  char* ws = (char*)d_ws;
  int*    bkt_cnt = (int*)ws;     ws += alignup(256 * 4);
  int*    bkt_off = (int*)ws;     ws += alignup(257 * 4);
  int*    gfront  = (int*)ws;     ws += alignup(256 * 4);
  int*    row_ptr = (int*)ws;     ws += alignup((size_t)(nN + 1) * 4);
  float*  dis     = (float*)ws;   ws += alignup((size_t)nN * 4);
  float*  Wf      = (float*)ws;   ws += alignup((size_t)NFEAT * NCP * 4);
  float*  bf      = (float*)ws;   ws += alignup((size_t)NCP * 4);
  ushort* Wt1     = (ushort*)ws;  ws += alignup((size_t)NFEAT * NFEAT * 2);
  ushort* Wt2     = (ushort*)ws;  ws += alignup((size_t)NFEAT * NFEAT * 2);
  int2*   binned  = (int2*)ws;    ws += alignup((size_t)total * 8);
  int*    ev      = (int*)ws;     ws += alignup((size_t)total * 4);
  ushort* hb      = (ushort*)ws;  ws += alignup((size_t)nN * NFEAT * 2);  // bf16 gather buffer
  float*  bufA    = (float*)ws;   ws += alignup((size_t)nN * NFEAT * 4);
  float*  G       = (float*)ws;   ws += alignup((size_t)nN * NCP * 4);

  // ---- CSR build
  zero_ints<<<1, 256, 0, stream>>>(bkt_cnt, nbkt);
  bucket_hist<<<512, 256, 0, stream>>>(ei + nE, bkt_cnt, nE, nbkt);
  bkt_scan<<<1, 256, 0, stream>>>(bkt_cnt, bkt_off, gfront, nN, nbkt);
  bin_items<<<nbBin, 256, 0, stream>>>(ei, nE, total, nbkt, gfront, binned);
  bucket_finalize<<<nbkt, BROW, 0, stream>>>(binned, bkt_off, row_ptr, dis, ev, nN, nbkt);

  // ---- weight prep
  fold_weights<<<8, 256, 0, stream>>>(W3, Wl, b3, bl, Wf, bf);
  prep_w<<<64, 256, 0, stream>>>(W1, Wt1);
  prep_w<<<64, 256, 0, stream>>>(W2, Wt2);

  const int gemm_grid = (nN + 63) / 64;
  const int node_grid = (nN + 3) / 4;

  // layer 1
  gemm_mfma<<<gemm_grid, 256, 0, stream>>>(x, Wt1, dis, hb, nN);
  aggregate<<<node_grid, 256, 0, stream>>>(hb, row_ptr, ev, dis, b1, bufA, 1, nN);
  // layer 2
  gemm_mfma<<<gemm_grid, 256, 0, stream>>>(bufA, Wt2, dis, hb, nN);
  aggregate<<<node_grid, 256, 0, stream>>>(hb, row_ptr, ev, dis, b2, bufA, 1, nN);
  // layer 3 folded with classifier: logits = dis*Agg(dis*(H2 @ (W3@Wl))) + (b3@Wl + bl)
  gemm_small<<<(nN + 255) / 256, 256, 0, stream>>>(bufA, Wf, dis, G, nN);
  agg_logits<<<node_grid, 256, 0, stream>>>(G, row_ptr, ev, dis, bf, out, nN);
}